// Round 16
// baseline (602.242 us; speedup 1.0000x reference)
//
#include <hip/hip_runtime.h>
#include <hip/hip_bf16.h>

#define NB   8
#define NPTS 8192
#define NT   2048
#define CWID 1024
#define DWID 256
#define NPBLK 256   // stat-partial blocks per stage

using f32x4  = __attribute__((ext_vector_type(4))) float;
using bf16x8 = __attribute__((ext_vector_type(8))) __bf16;
using bf16x4 = __attribute__((ext_vector_type(4))) __bf16;

// ---------------- ws layout (bytes) ----------------
#define OFF_INV    0u          // 8 f32 inv_p99
#define OFF_C      66560u      // 8x1024 f32
#define OFF_GB     99328u      // 22x8x256 f32 gamma/beta
#define OFF_STATS  279552u     // 512 f32 stats
#define OFF_W2T    1048576u    // 1024x1024 bf16 (W2 transposed)
#define OFF_WT     3145728u    // 10x256x256 bf16 (decoder W, n-major)
#define OFF_GBP    4456448u    // 22x16x8x256 f32 gb partials
#define OFF_PART   7340032u    // [512 cols][256 blocks] f32 stat partials (col-major)
#define OFF_IDX    8388608u    // 8x8192 i32 compacted valid-point indices
#define OFF_NV     8650752u    // 8 i32 valid counts
#define OFF_NET    19922944u   // 16384x256 f32  (aliases h1 pair during encoder, small path)
#define OFF_DX     36700160u   // 16384x256 f32
#define OFF_H1     19922944u   // small path: 2 x 8192x1024 bf16 = 32 MB (dead before fcp2)
#define OFF_H1F    67108864u   // big path: 8 x 8192x1024 bf16 = 128 MiB @ 64 MiB
#define WS_NEEDED  53477376u
#define WS_BIG     201326592u  // 192 MiB (h1 full ends at 64+128 MiB)

__device__ __forceinline__ void async_copy16(const void* g, void* l) {
  __builtin_amdgcn_global_load_lds(
      (const __attribute__((address_space(1))) unsigned int*)g,
      (__attribute__((address_space(3))) unsigned int*)l, 16, 0, 0);
}

// ====== p99 (4-pass radix select) + valid-point compaction + zero(c) ======
// idx slot order is atomic (non-deterministic) but downstream max-pool is
// order/duplicate-invariant, so the OUTPUT is deterministic.
__global__ __launch_bounds__(1024) void k_p99(
    const float* __restrict__ pts, float* __restrict__ inv_p99,
    int* __restrict__ idx, int* __restrict__ nv, float* __restrict__ c)
{
  const int b = blockIdx.x;
  const int t = threadIdx.x;
  __shared__ unsigned int keys[NPTS];
  __shared__ int whist[16][256];
  __shared__ int hist[256];
  __shared__ int s_cnt, s_kleft;
  __shared__ unsigned int s_prefix;

  c[b*CWID + t] = 0.f;   // zero pooled-feature buffer (1024 threads == CWID)
  if (t == 0) s_cnt = 0;
  __syncthreads();

  for (int n = t; n < NPTS; n += 1024) {
    const float x = pts[(b*NPTS + n)*3 + 0];
    const float y = pts[(b*NPTS + n)*3 + 1];
    const float z = pts[(b*NPTS + n)*3 + 2];
    const bool v = x > -50.f;
    unsigned int key = 0x7F800000u;  // +inf
    if (v) {
      key = __float_as_uint(sqrtf(x*x + y*y + z*z));
      const int slot = atomicAdd(&s_cnt, 1);
      idx[b*NPTS + slot] = n;
    }
    keys[n] = key;
  }
  __syncthreads();
  if (t == 0) {
    nv[b] = s_cnt;
    s_kleft = 1 + (int)rintf(0.99f * (float)(s_cnt - 1));
    s_prefix = 0u;
  }
  __syncthreads();

  const int w = t >> 6;
  for (int pass = 0; pass < 4; ++pass) {
    const int shift = 24 - 8*pass;
    const unsigned int pref = s_prefix;
    for (int i = t; i < 16*256; i += 1024) ((int*)whist)[i] = 0;
    __syncthreads();
    for (int n = t; n < NPTS; n += 1024) {
      const unsigned int key = keys[n];
      const bool m = (pass == 0) || ((key >> (shift + 8)) == (pref >> (shift + 8)));
      if (m) atomicAdd(&whist[w][(key >> shift) & 255], 1);
    }
    __syncthreads();
    if (t < 256) { int h = 0; for (int ww = 0; ww < 16; ++ww) h += whist[ww][t]; hist[t] = h; }
    __syncthreads();
    if (t < 64) {  // wave 0: parallel scan over 256 bins (4 per lane)
      const int kl = s_kleft;
      const int s0 = hist[t*4+0], s1 = hist[t*4+1], s2 = hist[t*4+2], s3 = hist[t*4+3];
      const int sl = s0 + s1 + s2 + s3;
      int p = sl;
      #pragma unroll
      for (int o = 1; o < 64; o <<= 1) { const int v = __shfl_up(p, o); if (t >= o) p += v; }
      const unsigned long long bl = __ballot(p >= kl);
      const int L = (int)(__ffsll((unsigned long long)bl) - 1);
      if (t == L) {
        int c0 = p - sl;
        int bin = t*4;
        if (c0 + s0 < kl) { c0 += s0; ++bin;
          if (c0 + s1 < kl) { c0 += s1; ++bin;
            if (c0 + s2 < kl) { c0 += s2; ++bin; } } }
        s_prefix = pref | ((unsigned int)bin << shift);
        s_kleft = kl - c0;
      }
    }
    __syncthreads();
  }
  if (t == 0) inv_p99[b] = 1.0f / __uint_as_float(s_prefix);
}

// ========= prep: W2 -> W2^T bf16 (tiles 0..255) + W0/W1 -> wt (256..415) =========
__global__ __launch_bounds__(256) void k_prep(
    const float* __restrict__ w2, __hip_bfloat16* __restrict__ w2t,
    const float* __restrict__ W0, const float* __restrict__ W1,
    __hip_bfloat16* __restrict__ wt)
{
  __shared__ float tile[64][65];
  const int bid = blockIdx.x;
  const int t = threadIdx.x;
  const int cc = t & 63, rq = t >> 6;
  if (bid < 256) {
    const int kb = (bid >> 4) * 64, nb = (bid & 15) * 64;
    #pragma unroll
    for (int i = 0; i < 16; ++i) {
      const int r = i*4 + rq;
      tile[r][cc] = w2[(kb + r)*CWID + nb + cc];
    }
    __syncthreads();
    #pragma unroll
    for (int i = 0; i < 16; ++i) {
      const int r = i*4 + rq;
      w2t[(size_t)(nb + r)*CWID + kb + cc] = __float2bfloat16(tile[cc][r]);
    }
  } else {
    const int idx = bid - 256;
    const int s = idx >> 4;
    const int kb = ((idx >> 2) & 3) * 64, nb = (idx & 3) * 64;
    const float* src = (s < 5) ? (W0 + (size_t)s*DWID*DWID) : (W1 + (size_t)(s-5)*DWID*DWID);
    #pragma unroll
    for (int i = 0; i < 16; ++i) {
      const int r = i*4 + rq;
      tile[r][cc] = src[(kb + r)*DWID + nb + cc];
    }
    __syncthreads();
    #pragma unroll
    for (int i = 0; i < 16; ++i) {
      const int r = i*4 + rq;
      wt[(size_t)s*DWID*DWID + (size_t)(nb + r)*DWID + kb + cc] = __float2bfloat16(tile[cc][r]);
    }
  }
}

// == encoder layer 1 (compacted rows, 16 rows/block) -> h1 bf16, 16B stores ==
#define E1R 16
__global__ __launch_bounds__(256) void k_enc1(
    const float* __restrict__ pts, const float* __restrict__ rgb,
    const float* __restrict__ inv_p99, const int* __restrict__ idx,
    const int* __restrict__ nv,
    const float* __restrict__ W1, const float* __restrict__ b1,
    __hip_bfloat16* __restrict__ h1, int b0)
{
  __shared__ float xs[E1R][6];
  const int z = blockIdx.y;
  const int b = b0 + z;
  const int nvb = nv[b];
  const int r0 = blockIdx.x * E1R;
  if (r0 >= ((nvb + 127) & ~127)) return;
  const int t = threadIdx.x;
  __hip_bfloat16* dst = h1 + (size_t)z*NPTS*CWID;
  if (t < E1R*6) {
    const int m = t / 6, j = t % 6;
    const int row = r0 + m;
    float val = 0.f;
    if (row < nvb) {
      const int gi = b*NPTS + idx[b*NPTS + row];
      const float inv = inv_p99[b];
      val = (j < 3) ? pts[gi*3 + j] * inv : rgb[gi*3 + j - 3];
    }
    xs[m][j] = val;
  }
  __syncthreads();
  #pragma unroll
  for (int k = 0; k < E1R/2; ++k) {
    const int ci = k*256 + t;
    const int m = ci >> 7;           // 0..E1R-1
    const bool vrow = (r0 + m) < nvb;
    const int coff = (ci & 127) * 8; // 8 cols per chunk
    const float x0 = xs[m][0], x1 = xs[m][1], x2 = xs[m][2];
    const float x3 = xs[m][3], x4 = xs[m][4], x5 = xs[m][5];
    f32x4 aA = *reinterpret_cast<const f32x4*>(&b1[coff]);
    f32x4 aB = *reinterpret_cast<const f32x4*>(&b1[coff + 4]);
    aA = aA + *reinterpret_cast<const f32x4*>(&W1[0*CWID + coff]) * x0;
    aB = aB + *reinterpret_cast<const f32x4*>(&W1[0*CWID + coff + 4]) * x0;
    aA = aA + *reinterpret_cast<const f32x4*>(&W1[1*CWID + coff]) * x1;
    aB = aB + *reinterpret_cast<const f32x4*>(&W1[1*CWID + coff + 4]) * x1;
    aA = aA + *reinterpret_cast<const f32x4*>(&W1[2*CWID + coff]) * x2;
    aB = aB + *reinterpret_cast<const f32x4*>(&W1[2*CWID + coff + 4]) * x2;
    aA = aA + *reinterpret_cast<const f32x4*>(&W1[3*CWID + coff]) * x3;
    aB = aB + *reinterpret_cast<const f32x4*>(&W1[3*CWID + coff + 4]) * x3;
    aA = aA + *reinterpret_cast<const f32x4*>(&W1[4*CWID + coff]) * x4;
    aB = aB + *reinterpret_cast<const f32x4*>(&W1[4*CWID + coff + 4]) * x4;
    aA = aA + *reinterpret_cast<const f32x4*>(&W1[5*CWID + coff]) * x5;
    aB = aB + *reinterpret_cast<const f32x4*>(&W1[5*CWID + coff + 4]) * x5;
    bf16x8 pk;
    #pragma unroll
    for (int u = 0; u < 4; ++u) pk[u]   = vrow ? (__bf16)fmaxf(aA[u], 0.f) : (__bf16)0.f;
    #pragma unroll
    for (int u = 0; u < 4; ++u) pk[4+u] = vrow ? (__bf16)fmaxf(aB[u], 0.f) : (__bf16)0.f;
    *reinterpret_cast<bf16x8*>(&dst[(size_t)(r0 + m)*CWID + coff]) = pk;
  }
}

// ===== encoder layer 2: 128x256 tile, 8 waves, A-dbuf LDS + B direct from L2 =====
// A LDS layout: 16B unit (row, logical octet ao) at addr16 = row*8 + (ao ^ (row&7)).
// B (w2t, 2 MB) is L2-resident: fragments read directly from global, overlapping
// MFMA with no barrier involvement. One __syncthreads per K-step: drains the
// A-prefetch issued a full iteration earlier (latency hidden by the MFMA loop).
#define EBM 128
#define EBN 256
#define EBK 64

__global__ __launch_bounds__(512) void k_enc2(
    const __hip_bfloat16* __restrict__ h1,   // [nz][8192][1024] compacted rows
    const __hip_bfloat16* __restrict__ w2t,  // [1024][1024] n-major
    const float* __restrict__ b2,
    const int* __restrict__ nv,
    float* __restrict__ c, int b0)           // [NB][CWID]
{
  __shared__ __align__(16) __hip_bfloat16 As[2][EBM*EBK];   // 2 x 16 KB
  const int t = threadIdx.x;
  const int lane = t & 63, wid = t >> 6;
  const int wm = wid >> 2, wn = wid & 3;     // 2 x 4 wave grid
  const int m0 = blockIdx.x * EBM;
  const int n0 = blockIdx.y * EBN;
  const int z  = blockIdx.z;
  const int b  = b0 + z;
  const int nvb = nv[b];
  if (m0 >= ((nvb + 127) & ~127)) return;   // whole tile is padding: skip
  const __hip_bfloat16* h1b = h1 + (size_t)z*NPTS*CWID;

  // A staging: 1024 16B-units, 2 per thread, octet-swizzled source
  #define STAGE_A(buf, kt) do {                                            \
    const int k0_ = (kt)*EBK;                                              \
    _Pragma("unroll")                                                      \
    for (int qq = 0; qq < 2; ++qq) {                                       \
      const int cib = qq*512 + wid*64;                                     \
      const int ci  = cib + lane;                                          \
      const int rw  = ci >> 3;                                             \
      const int oct = (ci & 7) ^ (rw & 7);                                 \
      async_copy16(h1b + (size_t)(m0 + rw)*CWID + k0_ + oct*8,             \
                   (__hip_bfloat16*)As[buf] + cib*8);                      \
    }                                                                      \
  } while (0)

  f32x4 acc[4][4] = {};

  STAGE_A(0, 0);
  for (int kt = 0; kt < 16; ++kt) {
    const int cur = kt & 1;
    __syncthreads();                 // A(cur) landed; buf[cur^1] readers done
    if (kt < 15) STAGE_A(cur^1, kt+1);
    #pragma unroll
    for (int ks = 0; ks < 2; ++ks) {
      const int ke = ks*32 + (lane >> 4)*8;
      const int ao = ke >> 3;
      bf16x8 a[4], bfr[4];
      #pragma unroll
      for (int f = 0; f < 4; ++f) {
        const int ar = wm*64 + f*16 + (lane & 15);
        const int brow = n0 + wn*64 + f*16 + (lane & 15);
        a[f]   = *reinterpret_cast<const bf16x8*>((char*)As[cur] + (ar*8 + (ao ^ (ar & 7)))*16);
        bfr[f] = *reinterpret_cast<const bf16x8*>(&w2t[(size_t)brow*CWID + kt*EBK + ke]);
      }
      #pragma unroll
      for (int fm = 0; fm < 4; ++fm)
        #pragma unroll
        for (int fn = 0; fn < 4; ++fn)
          acc[fm][fn] = __builtin_amdgcn_mfma_f32_16x16x32_bf16(a[fm], bfr[fn], acc[fm][fn], 0, 0, 0);
    }
  }
  #undef STAGE_A

  // epilogue: bias + relu + max over compacted rows (< nvb) -> atomicMax into c
  const int rbase = (lane >> 4)*4;
  #pragma unroll
  for (int fn = 0; fn < 4; ++fn) {
    const int gn = n0 + wn*64 + fn*16 + (lane & 15);
    const float bv = b2[gn];
    float mx = 0.f;
    #pragma unroll
    for (int fm = 0; fm < 4; ++fm) {
      const int gmb = m0 + wm*64 + fm*16 + rbase;
      #pragma unroll
      for (int r = 0; r < 4; ++r) {
        const float v = fmaxf(acc[fm][fn][r] + bv, 0.f);
        if (gmb + r < nvb) mx = fmaxf(mx, v);
      }
    }
    mx = fmaxf(mx, __shfl_xor(mx, 16));
    mx = fmaxf(mx, __shfl_xor(mx, 32));
    if ((lane >> 4) == 0)
      atomicMax((int*)(c + b*CWID + gn), __float_as_int(mx));  // values >= 0
  }
}

// ================= gamma/beta: stage A (split-K partials) =================
__global__ __launch_bounds__(256) void k_gbp(
    const float* __restrict__ c,
    const float* __restrict__ Wg0, const float* __restrict__ Wb0,
    const float* __restrict__ Wg1, const float* __restrict__ Wb1,
    const float* __restrict__ bnWg, const float* __restrict__ bnWb,
    float* __restrict__ gbp)
{
  __shared__ float cs[8][64];
  __shared__ float red[4][8][256];
  const int s  = blockIdx.y;
  const int kc = blockIdx.x;
  const int k0 = kc * 64;
  const int t  = threadIdx.x;

  const float* W;
  if      (s < 5)  W = Wg0 + (size_t)s*CWID*DWID;
  else if (s < 10) W = Wb0 + (size_t)(s-5)*CWID*DWID;
  else if (s < 15) W = Wg1 + (size_t)(s-10)*CWID*DWID;
  else if (s < 20) W = Wb1 + (size_t)(s-15)*CWID*DWID;
  else if (s == 20) W = bnWg;
  else              W = bnWb;

  {
    const int i0 = t*2;
    cs[i0 >> 6][i0 & 63]         = c[(i0 >> 6)*CWID + k0 + (i0 & 63)];
    cs[(i0+1) >> 6][(i0+1) & 63] = c[((i0+1) >> 6)*CWID + k0 + ((i0+1) & 63)];
  }
  __syncthreads();

  const int sub = t >> 6;
  const int c0  = (t & 63) * 4;
  f32x4 acc[8] = {};
  #pragma unroll
  for (int i = 0; i < 16; ++i) {
    const int kk = sub*16 + i;
    const f32x4 w = *reinterpret_cast<const f32x4*>(&W[(size_t)(k0 + kk)*DWID + c0]);
    #pragma unroll
    for (int b = 0; b < 8; ++b) acc[b] = acc[b] + w * cs[b][kk];
  }
  #pragma unroll
  for (int b = 0; b < 8; ++b)
    *reinterpret_cast<f32x4*>(&red[sub][b][c0]) = acc[b];
  __syncthreads();
  for (int b = 0; b < 8; ++b) {
    const float v = red[0][b][t] + red[1][b][t] + red[2][b][t] + red[3][b][t];
    gbp[(((size_t)s*16 + kc)*8 + b)*DWID + t] = v;
  }
}

// ================= gamma/beta: stage B (reduce + bias) =================
__global__ __launch_bounds__(256) void k_gbf(
    const float* __restrict__ gbp,
    const float* __restrict__ bg0, const float* __restrict__ bb0,
    const float* __restrict__ bg1, const float* __restrict__ bb1,
    const float* __restrict__ bnbg, const float* __restrict__ bnbb,
    float* __restrict__ gb)
{
  const int s = blockIdx.x;
  const int t = threadIdx.x;
  const float* bias;
  if      (s < 5)  bias = bg0 + s*DWID;
  else if (s < 10) bias = bb0 + (s-5)*DWID;
  else if (s < 15) bias = bg1 + (s-10)*DWID;
  else if (s < 20) bias = bb1 + (s-15)*DWID;
  else if (s == 20) bias = bnbg;
  else              bias = bnbb;
  const float bv = bias[t];
  for (int b = 0; b < 8; ++b) {
    float acc = bv;
    #pragma unroll
    for (int kc = 0; kc < 16; ++kc)
      acc += gbp[(((size_t)s*16 + kc)*8 + b)*DWID + t];
    gb[((size_t)s*8 + b)*DWID + t] = acc;
  }
}

// ================= fc_p (64 rows/block) + stat partials =================
__global__ __launch_bounds__(256) void k_fcp2(
    const float* __restrict__ qc, const float* __restrict__ inv_p99,
    const float* __restrict__ W, const float* __restrict__ bias,
    float* __restrict__ net, float* __restrict__ part)
{
  __shared__ float qs[192];
  const int blk = blockIdx.x;
  const int r0 = blk * 64;
  const int b = r0 >> 11;
  const int t = threadIdx.x;
  if (t < 192) qs[t] = qc[(size_t)r0*3 + t] * inv_p99[b];
  __syncthreads();
  const float w0 = W[t], w1 = W[DWID + t], w2 = W[2*DWID + t];
  const float bv = bias[t];
  float s = 0.f, q = 0.f;
  for (int m = 0; m < 64; ++m) {
    const float v = bv + qs[m*3]*w0 + qs[m*3+1]*w1 + qs[m*3+2]*w2;
    net[(size_t)(r0 + m)*DWID + t] = v;
    s += v; q += v*v;
  }
  part[(size_t)t*NPBLK + blk] = s;
  part[(size_t)(256 + t)*NPBLK + blk] = q;
}

// ====== stats finalize (32 blocks x 8 cols; contiguous col-major reads) ======
__global__ __launch_bounds__(256) void k_statf(
    const float* __restrict__ part, float* __restrict__ stats)
{
  const int t = threadIdx.x;
  const int j = t >> 5;            // col within block (0..7)
  const int lane = t & 31;
  const int col = blockIdx.x * 8 + j;
  const float* ps = part + (size_t)col*NPBLK;
  const float* pq = part + (size_t)(256 + col)*NPBLK;
  f32x4 sv = {}, qv = {};
  #pragma unroll
  for (int i = 0; i < 2; ++i) {
    sv = sv + *reinterpret_cast<const f32x4*>(ps + i*128 + lane*4);
    qv = qv + *reinterpret_cast<const f32x4*>(pq + i*128 + lane*4);
  }
  float s = (sv[0]+sv[1]) + (sv[2]+sv[3]);
  float q = (qv[0]+qv[1]) + (qv[2]+qv[3]);
  #pragma unroll
  for (int o = 16; o > 0; o >>= 1) { s += __shfl_down(s, o); q += __shfl_down(q, o); }
  if (lane == 0) {
    const float mean = s * (1.f/16384.f);
    const float var  = q * (1.f/16384.f) - mean*mean;
    stats[col] = mean;
    stats[256 + col] = rsqrtf(var + 1e-5f);
  }
}

// ========== CBN + relu + MFMA matmul (+residual) + stat partials ==========
// 64 rows/block: each block reads wt once (halved L2 traffic vs 32-row).
__global__ __launch_bounds__(256) void k_cbnmm(
    const float* __restrict__ X, const float* __restrict__ stats,
    const float* __restrict__ gb, int gslot, int bslot,
    const __hip_bfloat16* __restrict__ wt,   // [256 n][256 k] bf16
    const float* __restrict__ bias,
    float* __restrict__ out, int addmode, float* __restrict__ part)
{
  __shared__ __align__(16) __hip_bfloat16 xs[64 * 256];  // swizzled [row][k], 32 KB
  __shared__ float sred[4][2][128];
  const int t = threadIdx.x;
  const int blk = blockIdx.x;
  const int r0 = blk * 64;
  const int bb = r0 >> 11;

  // ---- stage: CBN + relu + bf16, XOR-swizzled on 16B groups ----
  {
    const int cq = (t & 63) * 4;
    const f32x4 mn = *reinterpret_cast<const f32x4*>(&stats[cq]);
    const f32x4 rs = *reinterpret_cast<const f32x4*>(&stats[256 + cq]);
    const f32x4 g  = *reinterpret_cast<const f32x4*>(&gb[((size_t)gslot*8 + bb)*DWID + cq]);
    const f32x4 be = *reinterpret_cast<const f32x4*>(&gb[((size_t)bslot*8 + bb)*DWID + cq]);
    const int rbase = t >> 6;
    #pragma unroll
    for (int j = 0; j < 16; ++j) {
      const int r = rbase + j*4;
      const f32x4 v = *reinterpret_cast<const f32x4*>(&X[(size_t)(r0 + r)*DWID + cq]);
      bf16x4 h;
      #pragma unroll
      for (int jj = 0; jj < 4; ++jj)
        h[jj] = (__bf16)fmaxf(0.f, (v[jj] - mn[jj])*rs[jj]*g[jj] + be[jj]);
      const int grp = (cq >> 3) ^ (r & 7);
      *reinterpret_cast<bf16x4*>((char*)xs + r*512 + grp*16 + (cq & 7)*2) = h;
    }
  }
  __syncthreads();

  const int lane = t & 63, wid = t >> 6;
  const int wm = wid >> 1, wn = wid & 1;
  f32x4 acc[2][8] = {};
  #pragma unroll
  for (int kstep = 0; kstep < 8; ++kstep) {
    const int ke = kstep*32 + (lane >> 4)*8;
    bf16x8 a[2], bfr[8];
    #pragma unroll
    for (int fm = 0; fm < 2; ++fm) {
      const int row = wm*32 + fm*16 + (lane & 15);
      a[fm] = *reinterpret_cast<const bf16x8*>(
          (char*)xs + row*512 + (((ke >> 3) ^ (row & 7))*16));
    }
    #pragma unroll
    for (int fn = 0; fn < 8; ++fn) {
      const int n = wn*128 + fn*16 + (lane & 15);
      bfr[fn] = *reinterpret_cast<const bf16x8*>(&wt[(size_t)n*DWID + ke]);
    }
    #pragma unroll
    for (int fm = 0; fm < 2; ++fm)
      #pragma unroll
      for (int fn = 0; fn < 8; ++fn)
        acc[fm][fn] = __builtin_amdgcn_mfma_f32_16x16x32_bf16(a[fm], bfr[fn], acc[fm][fn], 0, 0, 0);
  }

  // ---- epilogue: bias + residual + store + per-block column sums ----
  const int rb = (lane >> 4) * 4;
  #pragma unroll
  for (int fn = 0; fn < 8; ++fn) {
    const int gn = wn*128 + fn*16 + (lane & 15);
    const float bv = bias[gn];
    float s = 0.f, q = 0.f;
    #pragma unroll
    for (int fm = 0; fm < 2; ++fm) {
      const size_t row0 = (size_t)r0 + wm*32 + fm*16 + rb;
      #pragma unroll
      for (int r = 0; r < 4; ++r) {
        float v = acc[fm][fn][r] + bv;
        if (addmode) v += out[(row0 + r)*DWID + gn];
        out[(row0 + r)*DWID + gn] = v;
        s += v; q += v*v;
      }
    }
    s += __shfl_xor(s, 16); s += __shfl_xor(s, 32);
    q += __shfl_xor(q, 16); q += __shfl_xor(q, 32);
    if ((lane >> 4) == 0) {
      sred[wid][0][fn*16 + (lane & 15)] = s;
      sred[wid][1][fn*16 + (lane & 15)] = q;
    }
  }
  __syncthreads();
  {
    const int col = t;           // 0..255
    const int wn2 = col >> 7, cl = col & 127;
    const float s = sred[wn2][0][cl] + sred[2 + wn2][0][cl];
    const float q = sred[wn2][1][cl] + sred[2 + wn2][1][cl];
    part[(size_t)col*NPBLK + blk] = s;
    part[(size_t)(256 + col)*NPBLK + blk] = q;
  }
}

// ================= final CBN + relu + fc_out =================
__global__ __launch_bounds__(256) void k_final(
    const float* __restrict__ net, const float* __restrict__ stats,
    const float* __restrict__ gb, const float* __restrict__ fcW,
    const float* __restrict__ fcb, float* __restrict__ out)
{
  const int wid = threadIdx.x >> 6, lane = threadIdx.x & 63;
  const int m = blockIdx.x*4 + wid;
  const int b = m >> 11;
  const int f0 = lane*4;
  const f32x4 x  = *reinterpret_cast<const f32x4*>(&net[(size_t)m*DWID + f0]);
  const f32x4 mn = *reinterpret_cast<const f32x4*>(&stats[f0]);
  const f32x4 rs = *reinterpret_cast<const f32x4*>(&stats[256 + f0]);
  const f32x4 g  = *reinterpret_cast<const f32x4*>(&gb[(20*8 + (size_t)b)*DWID + f0]);
  const f32x4 be = *reinterpret_cast<const f32x4*>(&gb[(21*8 + (size_t)b)*DWID + f0]);
  const f32x4 w  = *reinterpret_cast<const f32x4*>(&fcW[f0]);
  float s = 0.f;
  #pragma unroll
  for (int j = 0; j < 4; ++j)
    s += fmaxf(0.f, (x[j] - mn[j])*rs[j]*g[j] + be[j]) * w[j];
  #pragma unroll
  for (int o = 32; o > 0; o >>= 1) s += __shfl_down(s, o);
  if (lane == 0) out[m] = s + fcb[0];
}

// ================= launch =================
extern "C" void kernel_launch(void* const* d_in, const int* in_sizes, int n_in,
                              void* d_out, int out_size, void* d_ws, size_t ws_size,
                              hipStream_t stream) {
  (void)in_sizes; (void)n_in; (void)out_size;
  if (ws_size < WS_NEEDED) return;

  const float* pts    = (const float*)d_in[0];
  const float* rgb    = (const float*)d_in[1];
  const float* qc     = (const float*)d_in[2];
  const float* enc_W1 = (const float*)d_in[3];
  const float* enc_b1 = (const float*)d_in[4];
  const float* enc_W2 = (const float*)d_in[5];
  const float* enc_b2 = (const float*)d_in[6];
  const float* fc_p_W = (const float*)d_in[7];
  const float* fc_p_b = (const float*)d_in[8];
  const float* Wg0 = (const float*)d_in[9];
  const float* bg0 = (const float*)d_in[10];
  const float* Wb0 = (const float*)d_in[11];
  const float* bb0 = (const float*)d_in[12];
  const float* W0  = (const float*)d_in[13];
  const float* b0  = (const float*)d_in[14];
  const float* Wg1 = (const float*)d_in[15];
  const float* bg1 = (const float*)d_in[16];
  const float* Wb1 = (const float*)d_in[17];
  const float* bb1 = (const float*)d_in[18];
  const float* W1  = (const float*)d_in[19];
  const float* b1  = (const float*)d_in[20];
  const float* bnWg = (const float*)d_in[21];
  const float* bnbg = (const float*)d_in[22];
  const float* bnWb = (const float*)d_in[23];
  const float* bnbb = (const float*)d_in[24];
  const float* fcoW = (const float*)d_in[25];
  const float* fcob = (const float*)d_in[26];
  float* out = (float*)d_out;

  char* ws = (char*)d_ws;
  float* inv_p99 = (float*)(ws + OFF_INV);
  float* c      = (float*)(ws + OFF_C);
  float* gbuf   = (float*)(ws + OFF_GB);
  float* stats  = (float*)(ws + OFF_STATS);
  __hip_bfloat16* w2t = (__hip_bfloat16*)(ws + OFF_W2T);
  __hip_bfloat16* wt  = (__hip_bfloat16*)(ws + OFF_WT);
  float* gbp  = (float*)(ws + OFF_GBP);
  float* part = (float*)(ws + OFF_PART);
  int*   idx  = (int*)(ws + OFF_IDX);
  int*   nvp  = (int*)(ws + OFF_NV);
  float* net = (float*)(ws + OFF_NET);
  float* dx  = (float*)(ws + OFF_DX);

  k_p99<<<NB, 1024, 0, stream>>>(pts, inv_p99, idx, nvp, c);
  k_prep<<<416, 256, 0, stream>>>(enc_W2, w2t, W0, W1, wt);

  if (ws_size >= WS_BIG) {
    // big path: full h1 at 64 MiB, single encoder launch over all 8 batches
    __hip_bfloat16* h1f = (__hip_bfloat16*)(ws + OFF_H1F);
    k_enc1<<<dim3(NPTS/E1R, NB), 256, 0, stream>>>(pts, rgb, inv_p99, idx, nvp,
                                                   enc_W1, enc_b1, h1f, 0);
    k_enc2<<<dim3(NPTS/EBM, CWID/EBN, NB), 512, 0, stream>>>(h1f, w2t, enc_b2,
                                                             nvp, c, 0);
  } else {
    // fallback: pair-looped encoder, h1 aliases net/dx
    __hip_bfloat16* h1 = (__hip_bfloat16*)(ws + OFF_H1);
    for (int bp = 0; bp < 4; ++bp) {
      k_enc1<<<dim3(NPTS/E1R, 2), 256, 0, stream>>>(pts, rgb, inv_p99, idx, nvp,
                                                    enc_W1, enc_b1, h1, bp*2);
      k_enc2<<<dim3(NPTS/EBM, CWID/EBN, 2), 512, 0, stream>>>(h1, w2t, enc_b2,
                                                              nvp, c, bp*2);
    }
  }

  k_gbp<<<dim3(16,22), 256, 0, stream>>>(c, Wg0, Wb0, Wg1, Wb1, bnWg, bnWb, gbp);
  k_gbf<<<22, 256, 0, stream>>>(gbp, bg0, bb0, bg1, bb1, bnbg, bnbb, gbuf);

  k_fcp2<<<NPBLK, 256, 0, stream>>>(qc, inv_p99, fc_p_W, fc_p_b, net, part);
  k_statf<<<32, 256, 0, stream>>>(part, stats);
  for (int i = 0; i < 5; ++i) {
    k_cbnmm<<<NPBLK, 256, 0, stream>>>(net, stats, gbuf, i, 5+i,
                                       wt + (size_t)i*DWID*DWID, b0 + i*DWID, dx, 0, part);
    k_statf<<<32, 256, 0, stream>>>(part, stats);
    k_cbnmm<<<NPBLK, 256, 0, stream>>>(dx, stats, gbuf, 10+i, 15+i,
                                       wt + (size_t)(5+i)*DWID*DWID, b1 + i*DWID, net, 1, part);
    k_statf<<<32, 256, 0, stream>>>(part, stats);
  }
  k_final<<<NB*NT/4, 256, 0, stream>>>(net, stats, gbuf, fcoW, fcob, out);
}

// Round 17
// 442.652 us; speedup vs baseline: 1.3605x; 1.3605x over previous
//
#include <hip/hip_runtime.h>
#include <hip/hip_bf16.h>

#define NB   8
#define NPTS 8192
#define NT   2048
#define CWID 1024
#define DWID 256
#define NPBLK 256   // stat-partial blocks per stage

using f32x4  = __attribute__((ext_vector_type(4))) float;
using bf16x8 = __attribute__((ext_vector_type(8))) __bf16;
using bf16x4 = __attribute__((ext_vector_type(4))) __bf16;

// ---------------- ws layout (bytes) ----------------
#define OFF_INV    0u          // 8 f32 inv_p99
#define OFF_C      66560u      // 8x1024 f32
#define OFF_GB     99328u      // 22x8x256 f32 gamma/beta
#define OFF_STATS  279552u     // 512 f32 stats
#define OFF_W2T    1048576u    // 1024x1024 bf16 (W2 transposed)
#define OFF_WT     3145728u    // 10x256x256 bf16 (decoder W, n-major)
#define OFF_GBP    4456448u    // 22x16x8x256 f32 gb partials
#define OFF_PART   7340032u    // [512 cols][256 blocks] f32 stat partials (col-major)
#define OFF_IDX    8388608u    // 8x8192 i32 compacted valid-point indices
#define OFF_NV     8650752u    // 8 i32 valid counts
#define OFF_NET    19922944u   // 16384x256 f32  (aliases h1 pair during encoder, small path)
#define OFF_DX     36700160u   // 16384x256 f32
#define OFF_H1     19922944u   // small path: 2 x 8192x1024 bf16 = 32 MB (dead before fcp2)
#define OFF_H1F    67108864u   // big path: 8 x 8192x1024 bf16 = 128 MiB @ 64 MiB
#define WS_NEEDED  53477376u
#define WS_BIG     201326592u  // 192 MiB (h1 full ends at 64+128 MiB)

__device__ __forceinline__ void async_copy16(const void* g, void* l) {
  __builtin_amdgcn_global_load_lds(
      (const __attribute__((address_space(1))) unsigned int*)g,
      (__attribute__((address_space(3))) unsigned int*)l, 16, 0, 0);
}

// ====== p99 (4-pass radix select) + valid-point compaction + zero(c) ======
// idx slot order is atomic (non-deterministic) but downstream max-pool is
// order/duplicate-invariant, so the OUTPUT is deterministic.
__global__ __launch_bounds__(1024) void k_p99(
    const float* __restrict__ pts, float* __restrict__ inv_p99,
    int* __restrict__ idx, int* __restrict__ nv, float* __restrict__ c)
{
  const int b = blockIdx.x;
  const int t = threadIdx.x;
  __shared__ unsigned int keys[NPTS];
  __shared__ int whist[16][256];
  __shared__ int hist[256];
  __shared__ int s_cnt, s_kleft;
  __shared__ unsigned int s_prefix;

  c[b*CWID + t] = 0.f;   // zero pooled-feature buffer (1024 threads == CWID)
  if (t == 0) s_cnt = 0;
  __syncthreads();

  for (int n = t; n < NPTS; n += 1024) {
    const float x = pts[(b*NPTS + n)*3 + 0];
    const float y = pts[(b*NPTS + n)*3 + 1];
    const float z = pts[(b*NPTS + n)*3 + 2];
    const bool v = x > -50.f;
    unsigned int key = 0x7F800000u;  // +inf
    if (v) {
      key = __float_as_uint(sqrtf(x*x + y*y + z*z));
      const int slot = atomicAdd(&s_cnt, 1);
      idx[b*NPTS + slot] = n;
    }
    keys[n] = key;
  }
  __syncthreads();
  if (t == 0) {
    nv[b] = s_cnt;
    s_kleft = 1 + (int)rintf(0.99f * (float)(s_cnt - 1));
    s_prefix = 0u;
  }
  __syncthreads();

  const int w = t >> 6;
  for (int pass = 0; pass < 4; ++pass) {
    const int shift = 24 - 8*pass;
    const unsigned int pref = s_prefix;
    for (int i = t; i < 16*256; i += 1024) ((int*)whist)[i] = 0;
    __syncthreads();
    for (int n = t; n < NPTS; n += 1024) {
      const unsigned int key = keys[n];
      const bool m = (pass == 0) || ((key >> (shift + 8)) == (pref >> (shift + 8)));
      if (m) atomicAdd(&whist[w][(key >> shift) & 255], 1);
    }
    __syncthreads();
    if (t < 256) { int h = 0; for (int ww = 0; ww < 16; ++ww) h += whist[ww][t]; hist[t] = h; }
    __syncthreads();
    if (t < 64) {  // wave 0: parallel scan over 256 bins (4 per lane)
      const int kl = s_kleft;
      const int s0 = hist[t*4+0], s1 = hist[t*4+1], s2 = hist[t*4+2], s3 = hist[t*4+3];
      const int sl = s0 + s1 + s2 + s3;
      int p = sl;
      #pragma unroll
      for (int o = 1; o < 64; o <<= 1) { const int v = __shfl_up(p, o); if (t >= o) p += v; }
      const unsigned long long bl = __ballot(p >= kl);
      const int L = (int)(__ffsll((unsigned long long)bl) - 1);
      if (t == L) {
        int c0 = p - sl;
        int bin = t*4;
        if (c0 + s0 < kl) { c0 += s0; ++bin;
          if (c0 + s1 < kl) { c0 += s1; ++bin;
            if (c0 + s2 < kl) { c0 += s2; ++bin; } } }
        s_prefix = pref | ((unsigned int)bin << shift);
        s_kleft = kl - c0;
      }
    }
    __syncthreads();
  }
  if (t == 0) inv_p99[b] = 1.0f / __uint_as_float(s_prefix);
}

// ========= prep: W2 -> W2^T bf16 (tiles 0..255) + W0/W1 -> wt (256..415) =========
__global__ __launch_bounds__(256) void k_prep(
    const float* __restrict__ w2, __hip_bfloat16* __restrict__ w2t,
    const float* __restrict__ W0, const float* __restrict__ W1,
    __hip_bfloat16* __restrict__ wt)
{
  __shared__ float tile[64][65];
  const int bid = blockIdx.x;
  const int t = threadIdx.x;
  const int cc = t & 63, rq = t >> 6;
  if (bid < 256) {
    const int kb = (bid >> 4) * 64, nb = (bid & 15) * 64;
    #pragma unroll
    for (int i = 0; i < 16; ++i) {
      const int r = i*4 + rq;
      tile[r][cc] = w2[(kb + r)*CWID + nb + cc];
    }
    __syncthreads();
    #pragma unroll
    for (int i = 0; i < 16; ++i) {
      const int r = i*4 + rq;
      w2t[(size_t)(nb + r)*CWID + kb + cc] = __float2bfloat16(tile[cc][r]);
    }
  } else {
    const int idx = bid - 256;
    const int s = idx >> 4;
    const int kb = ((idx >> 2) & 3) * 64, nb = (idx & 3) * 64;
    const float* src = (s < 5) ? (W0 + (size_t)s*DWID*DWID) : (W1 + (size_t)(s-5)*DWID*DWID);
    #pragma unroll
    for (int i = 0; i < 16; ++i) {
      const int r = i*4 + rq;
      tile[r][cc] = src[(kb + r)*DWID + nb + cc];
    }
    __syncthreads();
    #pragma unroll
    for (int i = 0; i < 16; ++i) {
      const int r = i*4 + rq;
      wt[(size_t)s*DWID*DWID + (size_t)(nb + r)*DWID + kb + cc] = __float2bfloat16(tile[cc][r]);
    }
  }
}

// == encoder layer 1 (compacted rows, 16 rows/block) -> h1 bf16, 16B stores ==
#define E1R 16
__global__ __launch_bounds__(256) void k_enc1(
    const float* __restrict__ pts, const float* __restrict__ rgb,
    const float* __restrict__ inv_p99, const int* __restrict__ idx,
    const int* __restrict__ nv,
    const float* __restrict__ W1, const float* __restrict__ b1,
    __hip_bfloat16* __restrict__ h1, int b0)
{
  __shared__ float xs[E1R][6];
  const int z = blockIdx.y;
  const int b = b0 + z;
  const int nvb = nv[b];
  const int r0 = blockIdx.x * E1R;
  if (r0 >= ((nvb + 127) & ~127)) return;
  const int t = threadIdx.x;
  __hip_bfloat16* dst = h1 + (size_t)z*NPTS*CWID;
  if (t < E1R*6) {
    const int m = t / 6, j = t % 6;
    const int row = r0 + m;
    float val = 0.f;
    if (row < nvb) {
      const int gi = b*NPTS + idx[b*NPTS + row];
      const float inv = inv_p99[b];
      val = (j < 3) ? pts[gi*3 + j] * inv : rgb[gi*3 + j - 3];
    }
    xs[m][j] = val;
  }
  __syncthreads();
  #pragma unroll
  for (int k = 0; k < E1R/2; ++k) {
    const int ci = k*256 + t;
    const int m = ci >> 7;           // 0..E1R-1
    const bool vrow = (r0 + m) < nvb;
    const int coff = (ci & 127) * 8; // 8 cols per chunk
    const float x0 = xs[m][0], x1 = xs[m][1], x2 = xs[m][2];
    const float x3 = xs[m][3], x4 = xs[m][4], x5 = xs[m][5];
    f32x4 aA = *reinterpret_cast<const f32x4*>(&b1[coff]);
    f32x4 aB = *reinterpret_cast<const f32x4*>(&b1[coff + 4]);
    aA = aA + *reinterpret_cast<const f32x4*>(&W1[0*CWID + coff]) * x0;
    aB = aB + *reinterpret_cast<const f32x4*>(&W1[0*CWID + coff + 4]) * x0;
    aA = aA + *reinterpret_cast<const f32x4*>(&W1[1*CWID + coff]) * x1;
    aB = aB + *reinterpret_cast<const f32x4*>(&W1[1*CWID + coff + 4]) * x1;
    aA = aA + *reinterpret_cast<const f32x4*>(&W1[2*CWID + coff]) * x2;
    aB = aB + *reinterpret_cast<const f32x4*>(&W1[2*CWID + coff + 4]) * x2;
    aA = aA + *reinterpret_cast<const f32x4*>(&W1[3*CWID + coff]) * x3;
    aB = aB + *reinterpret_cast<const f32x4*>(&W1[3*CWID + coff + 4]) * x3;
    aA = aA + *reinterpret_cast<const f32x4*>(&W1[4*CWID + coff]) * x4;
    aB = aB + *reinterpret_cast<const f32x4*>(&W1[4*CWID + coff + 4]) * x4;
    aA = aA + *reinterpret_cast<const f32x4*>(&W1[5*CWID + coff]) * x5;
    aB = aB + *reinterpret_cast<const f32x4*>(&W1[5*CWID + coff + 4]) * x5;
    bf16x8 pk;
    #pragma unroll
    for (int u = 0; u < 4; ++u) pk[u]   = vrow ? (__bf16)fmaxf(aA[u], 0.f) : (__bf16)0.f;
    #pragma unroll
    for (int u = 0; u < 4; ++u) pk[4+u] = vrow ? (__bf16)fmaxf(aB[u], 0.f) : (__bf16)0.f;
    *reinterpret_cast<bf16x8*>(&dst[(size_t)(r0 + m)*CWID + coff]) = pk;
  }
}

// ===== encoder layer 2: 128x256 tile, 8 waves, octet-swizzled LDS + max-pool =====
// LDS layout: 16B unit (row, logical octet ao) at addr16 = row*8 + (ao ^ (row&7)).
// (Round-15 proven structure: 104.7 us, 920 TF. B-direct-from-L2 variant was
//  2.5x WORSE — L2 latency on the MFMA critical path; keep LDS staging.)
#define EBM 128
#define EBN 256
#define EBK 64

__global__ __launch_bounds__(512) void k_enc2(
    const __hip_bfloat16* __restrict__ h1,   // [nz][8192][1024] compacted rows
    const __hip_bfloat16* __restrict__ w2t,  // [1024][1024] n-major
    const float* __restrict__ b2,
    const int* __restrict__ nv,
    float* __restrict__ c, int b0)           // [NB][CWID]
{
  __shared__ __align__(16) __hip_bfloat16 As[EBM*EBK];   // 16 KB
  __shared__ __align__(16) __hip_bfloat16 Bs[EBN*EBK];   // 32 KB
  const int t = threadIdx.x;
  const int lane = t & 63, wid = t >> 6;
  const int wm = wid >> 2, wn = wid & 3;     // 2 x 4 wave grid
  const int m0 = blockIdx.x * EBM;
  const int n0 = blockIdx.y * EBN;
  const int z  = blockIdx.z;
  const int b  = b0 + z;
  const int nvb = nv[b];
  if (m0 >= ((nvb + 127) & ~127)) return;   // whole tile is padding: skip
  const __hip_bfloat16* h1b = h1 + (size_t)z*NPTS*CWID;

  f32x4 acc[4][4] = {};

  for (int kt = 0; kt < 16; ++kt) {
    {
      const int k0_ = kt*EBK;
      // A: 1024 16B-units, 2 per thread
      #pragma unroll
      for (int qq = 0; qq < 2; ++qq) {
        const int cib = qq*512 + wid*64;     // wave-uniform dest base
        const int ci  = cib + lane;
        const int rw  = ci >> 3;
        const int oct = (ci & 7) ^ (rw & 7);
        async_copy16(h1b + (size_t)(m0 + rw)*CWID + k0_ + oct*8,
                     (__hip_bfloat16*)As + cib*8);
      }
      // B: 2048 16B-units, 4 per thread
      #pragma unroll
      for (int qq = 0; qq < 4; ++qq) {
        const int cib = qq*512 + wid*64;
        const int ci  = cib + lane;
        const int rw  = ci >> 3;
        const int oct = (ci & 7) ^ (rw & 7);
        async_copy16(w2t + (size_t)(n0 + rw)*CWID + k0_ + oct*8,
                     (__hip_bfloat16*)Bs + cib*8);
      }
    }
    __syncthreads();   // drains global_load_lds (vmcnt) + barrier: buffer ready
    #pragma unroll
    for (int ks = 0; ks < 2; ++ks) {
      const int ke = ks*32 + (lane >> 4)*8;
      const int ao = ke >> 3;
      bf16x8 a[4], bfr[4];
      #pragma unroll
      for (int f = 0; f < 4; ++f) {
        const int ar = wm*64 + f*16 + (lane & 15);
        const int br = wn*64 + f*16 + (lane & 15);
        a[f]   = *reinterpret_cast<const bf16x8*>((char*)As + (ar*8 + (ao ^ (ar & 7)))*16);
        bfr[f] = *reinterpret_cast<const bf16x8*>((char*)Bs + (br*8 + (ao ^ (br & 7)))*16);
      }
      #pragma unroll
      for (int fm = 0; fm < 4; ++fm)
        #pragma unroll
        for (int fn = 0; fn < 4; ++fn)
          acc[fm][fn] = __builtin_amdgcn_mfma_f32_16x16x32_bf16(a[fm], bfr[fn], acc[fm][fn], 0, 0, 0);
    }
    __syncthreads();   // all readers done before next STAGE overwrites
  }

  // epilogue: bias + relu + max over compacted rows (< nvb) -> atomicMax into c
  const int rbase = (lane >> 4)*4;
  #pragma unroll
  for (int fn = 0; fn < 4; ++fn) {
    const int gn = n0 + wn*64 + fn*16 + (lane & 15);
    const float bv = b2[gn];
    float mx = 0.f;
    #pragma unroll
    for (int fm = 0; fm < 4; ++fm) {
      const int gmb = m0 + wm*64 + fm*16 + rbase;
      #pragma unroll
      for (int r = 0; r < 4; ++r) {
        const float v = fmaxf(acc[fm][fn][r] + bv, 0.f);
        if (gmb + r < nvb) mx = fmaxf(mx, v);
      }
    }
    mx = fmaxf(mx, __shfl_xor(mx, 16));
    mx = fmaxf(mx, __shfl_xor(mx, 32));
    if ((lane >> 4) == 0)
      atomicMax((int*)(c + b*CWID + gn), __float_as_int(mx));  // values >= 0
  }
}

// ================= gamma/beta: stage A (split-K partials) =================
__global__ __launch_bounds__(256) void k_gbp(
    const float* __restrict__ c,
    const float* __restrict__ Wg0, const float* __restrict__ Wb0,
    const float* __restrict__ Wg1, const float* __restrict__ Wb1,
    const float* __restrict__ bnWg, const float* __restrict__ bnWb,
    float* __restrict__ gbp)
{
  __shared__ float cs[8][64];
  __shared__ float red[4][8][256];
  const int s  = blockIdx.y;
  const int kc = blockIdx.x;
  const int k0 = kc * 64;
  const int t  = threadIdx.x;

  const float* W;
  if      (s < 5)  W = Wg0 + (size_t)s*CWID*DWID;
  else if (s < 10) W = Wb0 + (size_t)(s-5)*CWID*DWID;
  else if (s < 15) W = Wg1 + (size_t)(s-10)*CWID*DWID;
  else if (s < 20) W = Wb1 + (size_t)(s-15)*CWID*DWID;
  else if (s == 20) W = bnWg;
  else              W = bnWb;

  {
    const int i0 = t*2;
    cs[i0 >> 6][i0 & 63]         = c[(i0 >> 6)*CWID + k0 + (i0 & 63)];
    cs[(i0+1) >> 6][(i0+1) & 63] = c[((i0+1) >> 6)*CWID + k0 + ((i0+1) & 63)];
  }
  __syncthreads();

  const int sub = t >> 6;
  const int c0  = (t & 63) * 4;
  f32x4 acc[8] = {};
  #pragma unroll
  for (int i = 0; i < 16; ++i) {
    const int kk = sub*16 + i;
    const f32x4 w = *reinterpret_cast<const f32x4*>(&W[(size_t)(k0 + kk)*DWID + c0]);
    #pragma unroll
    for (int b = 0; b < 8; ++b) acc[b] = acc[b] + w * cs[b][kk];
  }
  #pragma unroll
  for (int b = 0; b < 8; ++b)
    *reinterpret_cast<f32x4*>(&red[sub][b][c0]) = acc[b];
  __syncthreads();
  for (int b = 0; b < 8; ++b) {
    const float v = red[0][b][t] + red[1][b][t] + red[2][b][t] + red[3][b][t];
    gbp[(((size_t)s*16 + kc)*8 + b)*DWID + t] = v;
  }
}

// ================= gamma/beta: stage B (reduce + bias) =================
__global__ __launch_bounds__(256) void k_gbf(
    const float* __restrict__ gbp,
    const float* __restrict__ bg0, const float* __restrict__ bb0,
    const float* __restrict__ bg1, const float* __restrict__ bb1,
    const float* __restrict__ bnbg, const float* __restrict__ bnbb,
    float* __restrict__ gb)
{
  const int s = blockIdx.x;
  const int t = threadIdx.x;
  const float* bias;
  if      (s < 5)  bias = bg0 + s*DWID;
  else if (s < 10) bias = bb0 + (s-5)*DWID;
  else if (s < 15) bias = bg1 + (s-10)*DWID;
  else if (s < 20) bias = bb1 + (s-15)*DWID;
  else if (s == 20) bias = bnbg;
  else              bias = bnbb;
  const float bv = bias[t];
  for (int b = 0; b < 8; ++b) {
    float acc = bv;
    #pragma unroll
    for (int kc = 0; kc < 16; ++kc)
      acc += gbp[(((size_t)s*16 + kc)*8 + b)*DWID + t];
    gb[((size_t)s*8 + b)*DWID + t] = acc;
  }
}

// ================= fc_p (64 rows/block) + stat partials =================
__global__ __launch_bounds__(256) void k_fcp2(
    const float* __restrict__ qc, const float* __restrict__ inv_p99,
    const float* __restrict__ W, const float* __restrict__ bias,
    float* __restrict__ net, float* __restrict__ part)
{
  __shared__ float qs[192];
  const int blk = blockIdx.x;
  const int r0 = blk * 64;
  const int b = r0 >> 11;
  const int t = threadIdx.x;
  if (t < 192) qs[t] = qc[(size_t)r0*3 + t] * inv_p99[b];
  __syncthreads();
  const float w0 = W[t], w1 = W[DWID + t], w2 = W[2*DWID + t];
  const float bv = bias[t];
  float s = 0.f, q = 0.f;
  for (int m = 0; m < 64; ++m) {
    const float v = bv + qs[m*3]*w0 + qs[m*3+1]*w1 + qs[m*3+2]*w2;
    net[(size_t)(r0 + m)*DWID + t] = v;
    s += v; q += v*v;
  }
  part[(size_t)t*NPBLK + blk] = s;
  part[(size_t)(256 + t)*NPBLK + blk] = q;
}

// ====== stats finalize (32 blocks x 8 cols; contiguous col-major reads) ======
__global__ __launch_bounds__(256) void k_statf(
    const float* __restrict__ part, float* __restrict__ stats)
{
  const int t = threadIdx.x;
  const int j = t >> 5;            // col within block (0..7)
  const int lane = t & 31;
  const int col = blockIdx.x * 8 + j;
  const float* ps = part + (size_t)col*NPBLK;
  const float* pq = part + (size_t)(256 + col)*NPBLK;
  f32x4 sv = {}, qv = {};
  #pragma unroll
  for (int i = 0; i < 2; ++i) {
    sv = sv + *reinterpret_cast<const f32x4*>(ps + i*128 + lane*4);
    qv = qv + *reinterpret_cast<const f32x4*>(pq + i*128 + lane*4);
  }
  float s = (sv[0]+sv[1]) + (sv[2]+sv[3]);
  float q = (qv[0]+qv[1]) + (qv[2]+qv[3]);
  #pragma unroll
  for (int o = 16; o > 0; o >>= 1) { s += __shfl_down(s, o); q += __shfl_down(q, o); }
  if (lane == 0) {
    const float mean = s * (1.f/16384.f);
    const float var  = q * (1.f/16384.f) - mean*mean;
    stats[col] = mean;
    stats[256 + col] = rsqrtf(var + 1e-5f);
  }
}

// ========== CBN + relu + MFMA matmul (+residual) + stat partials ==========
// 64 rows/block: each block reads wt once (halved L2 traffic vs 32-row).
__global__ __launch_bounds__(256) void k_cbnmm(
    const float* __restrict__ X, const float* __restrict__ stats,
    const float* __restrict__ gb, int gslot, int bslot,
    const __hip_bfloat16* __restrict__ wt,   // [256 n][256 k] bf16
    const float* __restrict__ bias,
    float* __restrict__ out, int addmode, float* __restrict__ part)
{
  __shared__ __align__(16) __hip_bfloat16 xs[64 * 256];  // swizzled [row][k], 32 KB
  __shared__ float sred[4][2][128];
  const int t = threadIdx.x;
  const int blk = blockIdx.x;
  const int r0 = blk * 64;
  const int bb = r0 >> 11;

  // ---- stage: CBN + relu + bf16, XOR-swizzled on 16B groups ----
  {
    const int cq = (t & 63) * 4;
    const f32x4 mn = *reinterpret_cast<const f32x4*>(&stats[cq]);
    const f32x4 rs = *reinterpret_cast<const f32x4*>(&stats[256 + cq]);
    const f32x4 g  = *reinterpret_cast<const f32x4*>(&gb[((size_t)gslot*8 + bb)*DWID + cq]);
    const f32x4 be = *reinterpret_cast<const f32x4*>(&gb[((size_t)bslot*8 + bb)*DWID + cq]);
    const int rbase = t >> 6;
    #pragma unroll
    for (int j = 0; j < 16; ++j) {
      const int r = rbase + j*4;
      const f32x4 v = *reinterpret_cast<const f32x4*>(&X[(size_t)(r0 + r)*DWID + cq]);
      bf16x4 h;
      #pragma unroll
      for (int jj = 0; jj < 4; ++jj)
        h[jj] = (__bf16)fmaxf(0.f, (v[jj] - mn[jj])*rs[jj]*g[jj] + be[jj]);
      const int grp = (cq >> 3) ^ (r & 7);
      *reinterpret_cast<bf16x4*>((char*)xs + r*512 + grp*16 + (cq & 7)*2) = h;
    }
  }
  __syncthreads();

  const int lane = t & 63, wid = t >> 6;
  const int wm = wid >> 1, wn = wid & 1;
  f32x4 acc[2][8] = {};
  #pragma unroll
  for (int kstep = 0; kstep < 8; ++kstep) {
    const int ke = kstep*32 + (lane >> 4)*8;
    bf16x8 a[2], bfr[8];
    #pragma unroll
    for (int fm = 0; fm < 2; ++fm) {
      const int row = wm*32 + fm*16 + (lane & 15);
      a[fm] = *reinterpret_cast<const bf16x8*>(
          (char*)xs + row*512 + (((ke >> 3) ^ (row & 7))*16));
    }
    #pragma unroll
    for (int fn = 0; fn < 8; ++fn) {
      const int n = wn*128 + fn*16 + (lane & 15);
      bfr[fn] = *reinterpret_cast<const bf16x8*>(&wt[(size_t)n*DWID + ke]);
    }
    #pragma unroll
    for (int fm = 0; fm < 2; ++fm)
      #pragma unroll
      for (int fn = 0; fn < 8; ++fn)
        acc[fm][fn] = __builtin_amdgcn_mfma_f32_16x16x32_bf16(a[fm], bfr[fn], acc[fm][fn], 0, 0, 0);
  }

  // ---- epilogue: bias + residual + store + per-block column sums ----
  const int rb = (lane >> 4) * 4;
  #pragma unroll
  for (int fn = 0; fn < 8; ++fn) {
    const int gn = wn*128 + fn*16 + (lane & 15);
    const float bv = bias[gn];
    float s = 0.f, q = 0.f;
    #pragma unroll
    for (int fm = 0; fm < 2; ++fm) {
      const size_t row0 = (size_t)r0 + wm*32 + fm*16 + rb;
      #pragma unroll
      for (int r = 0; r < 4; ++r) {
        float v = acc[fm][fn][r] + bv;
        if (addmode) v += out[(row0 + r)*DWID + gn];
        out[(row0 + r)*DWID + gn] = v;
        s += v; q += v*v;
      }
    }
    s += __shfl_xor(s, 16); s += __shfl_xor(s, 32);
    q += __shfl_xor(q, 16); q += __shfl_xor(q, 32);
    if ((lane >> 4) == 0) {
      sred[wid][0][fn*16 + (lane & 15)] = s;
      sred[wid][1][fn*16 + (lane & 15)] = q;
    }
  }
  __syncthreads();
  {
    const int col = t;           // 0..255
    const int wn2 = col >> 7, cl = col & 127;
    const float s = sred[wn2][0][cl] + sred[2 + wn2][0][cl];
    const float q = sred[wn2][1][cl] + sred[2 + wn2][1][cl];
    part[(size_t)col*NPBLK + blk] = s;
    part[(size_t)(256 + col)*NPBLK + blk] = q;
  }
}

// ================= final CBN + relu + fc_out =================
__global__ __launch_bounds__(256) void k_final(
    const float* __restrict__ net, const float* __restrict__ stats,
    const float* __restrict__ gb, const float* __restrict__ fcW,
    const float* __restrict__ fcb, float* __restrict__ out)
{
  const int wid = threadIdx.x >> 6, lane = threadIdx.x & 63;
  const int m = blockIdx.x*4 + wid;
  const int b = m >> 11;
  const int f0 = lane*4;
  const f32x4 x  = *reinterpret_cast<const f32x4*>(&net[(size_t)m*DWID + f0]);
  const f32x4 mn = *reinterpret_cast<const f32x4*>(&stats[f0]);
  const f32x4 rs = *reinterpret_cast<const f32x4*>(&stats[256 + f0]);
  const f32x4 g  = *reinterpret_cast<const f32x4*>(&gb[(20*8 + (size_t)b)*DWID + f0]);
  const f32x4 be = *reinterpret_cast<const f32x4*>(&gb[(21*8 + (size_t)b)*DWID + f0]);
  const f32x4 w  = *reinterpret_cast<const f32x4*>(&fcW[f0]);
  float s = 0.f;
  #pragma unroll
  for (int j = 0; j < 4; ++j)
    s += fmaxf(0.f, (x[j] - mn[j])*rs[j]*g[j] + be[j]) * w[j];
  #pragma unroll
  for (int o = 32; o > 0; o >>= 1) s += __shfl_down(s, o);
  if (lane == 0) out[m] = s + fcb[0];
}

// ================= launch =================
extern "C" void kernel_launch(void* const* d_in, const int* in_sizes, int n_in,
                              void* d_out, int out_size, void* d_ws, size_t ws_size,
                              hipStream_t stream) {
  (void)in_sizes; (void)n_in; (void)out_size;
  if (ws_size < WS_NEEDED) return;

  const float* pts    = (const float*)d_in[0];
  const float* rgb    = (const float*)d_in[1];
  const float* qc     = (const float*)d_in[2];
  const float* enc_W1 = (const float*)d_in[3];
  const float* enc_b1 = (const float*)d_in[4];
  const float* enc_W2 = (const float*)d_in[5];
  const float* enc_b2 = (const float*)d_in[6];
  const float* fc_p_W = (const float*)d_in[7];
  const float* fc_p_b = (const float*)d_in[8];
  const float* Wg0 = (const float*)d_in[9];
  const float* bg0 = (const float*)d_in[10];
  const float* Wb0 = (const float*)d_in[11];
  const float* bb0 = (const float*)d_in[12];
  const float* W0  = (const float*)d_in[13];
  const float* b0  = (const float*)d_in[14];
  const float* Wg1 = (const float*)d_in[15];
  const float* bg1 = (const float*)d_in[16];
  const float* Wb1 = (const float*)d_in[17];
  const float* bb1 = (const float*)d_in[18];
  const float* W1  = (const float*)d_in[19];
  const float* b1  = (const float*)d_in[20];
  const float* bnWg = (const float*)d_in[21];
  const float* bnbg = (const float*)d_in[22];
  const float* bnWb = (const float*)d_in[23];
  const float* bnbb = (const float*)d_in[24];
  const float* fcoW = (const float*)d_in[25];
  const float* fcob = (const float*)d_in[26];
  float* out = (float*)d_out;

  char* ws = (char*)d_ws;
  float* inv_p99 = (float*)(ws + OFF_INV);
  float* c      = (float*)(ws + OFF_C);
  float* gbuf   = (float*)(ws + OFF_GB);
  float* stats  = (float*)(ws + OFF_STATS);
  __hip_bfloat16* w2t = (__hip_bfloat16*)(ws + OFF_W2T);
  __hip_bfloat16* wt  = (__hip_bfloat16*)(ws + OFF_WT);
  float* gbp  = (float*)(ws + OFF_GBP);
  float* part = (float*)(ws + OFF_PART);
  int*   idx  = (int*)(ws + OFF_IDX);
  int*   nvp  = (int*)(ws + OFF_NV);
  float* net = (float*)(ws + OFF_NET);
  float* dx  = (float*)(ws + OFF_DX);

  k_p99<<<NB, 1024, 0, stream>>>(pts, inv_p99, idx, nvp, c);
  k_prep<<<416, 256, 0, stream>>>(enc_W2, w2t, W0, W1, wt);

  if (ws_size >= WS_BIG) {
    // big path: full h1 at 64 MiB, single encoder launch over all 8 batches
    __hip_bfloat16* h1f = (__hip_bfloat16*)(ws + OFF_H1F);
    k_enc1<<<dim3(NPTS/E1R, NB), 256, 0, stream>>>(pts, rgb, inv_p99, idx, nvp,
                                                   enc_W1, enc_b1, h1f, 0);
    k_enc2<<<dim3(NPTS/EBM, CWID/EBN, NB), 512, 0, stream>>>(h1f, w2t, enc_b2,
                                                             nvp, c, 0);
  } else {
    // fallback: pair-looped encoder, h1 aliases net/dx
    __hip_bfloat16* h1 = (__hip_bfloat16*)(ws + OFF_H1);
    for (int bp = 0; bp < 4; ++bp) {
      k_enc1<<<dim3(NPTS/E1R, 2), 256, 0, stream>>>(pts, rgb, inv_p99, idx, nvp,
                                                    enc_W1, enc_b1, h1, bp*2);
      k_enc2<<<dim3(NPTS/EBM, CWID/EBN, 2), 512, 0, stream>>>(h1, w2t, enc_b2,
                                                              nvp, c, bp*2);
    }
  }

  k_gbp<<<dim3(16,22), 256, 0, stream>>>(c, Wg0, Wb0, Wg1, Wb1, bnWg, bnWb, gbp);
  k_gbf<<<22, 256, 0, stream>>>(gbp, bg0, bb0, bg1, bb1, bnbg, bnbb, gbuf);

  k_fcp2<<<NPBLK, 256, 0, stream>>>(qc, inv_p99, fc_p_W, fc_p_b, net, part);
  k_statf<<<32, 256, 0, stream>>>(part, stats);
  for (int i = 0; i < 5; ++i) {
    k_cbnmm<<<NPBLK, 256, 0, stream>>>(net, stats, gbuf, i, 5+i,
                                       wt + (size_t)i*DWID*DWID, b0 + i*DWID, dx, 0, part);
    k_statf<<<32, 256, 0, stream>>>(part, stats);
    k_cbnmm<<<NPBLK, 256, 0, stream>>>(dx, stats, gbuf, 10+i, 15+i,
                                       wt + (size_t)(5+i)*DWID*DWID, b1 + i*DWID, net, 1, part);
    k_statf<<<32, 256, 0, stream>>>(part, stats);
  }
  k_final<<<NB*NT/4, 256, 0, stream>>>(net, stats, gbuf, fcoW, fcob, out);
}

// Round 18
// 442.208 us; speedup vs baseline: 1.3619x; 1.0010x over previous
//
#include <hip/hip_runtime.h>
#include <hip/hip_bf16.h>

#define NB   8
#define NPTS 8192
#define NT   2048
#define CWID 1024
#define DWID 256
#define NPBLK 256   // stat-partial blocks per stage

using f32x4  = __attribute__((ext_vector_type(4))) float;
using bf16x8 = __attribute__((ext_vector_type(8))) __bf16;
using bf16x4 = __attribute__((ext_vector_type(4))) __bf16;

// ---------------- ws layout (bytes) ----------------
#define OFF_INV    0u          // 8 f32 inv_p99
#define OFF_C      66560u      // 8x1024 f32
#define OFF_GB     99328u      // 22x8x256 f32 gamma/beta
#define OFF_STATS  279552u     // 512 f32 stats
#define OFF_W2T    1048576u    // 1024x1024 bf16 (W2 transposed)
#define OFF_WT     3145728u    // 10x256x256 bf16 (decoder W, n-major)
#define OFF_GBP    4456448u    // 22x16x8x256 f32 gb partials
#define OFF_PART   7340032u    // [512 cols][256 blocks] f32 stat partials (col-major)
#define OFF_IDX    8388608u    // 8x8192 i32 compacted valid-point indices
#define OFF_NV     8650752u    // 8 i32 valid counts
#define OFF_NET    19922944u   // 16384x256 f32  (aliases h1 pair during encoder, small path)
#define OFF_DX     36700160u   // 16384x256 f32
#define OFF_H1     19922944u   // small path: 2 x 8192x1024 bf16 = 32 MB (dead before fcp2)
#define OFF_H1F    67108864u   // big path: 8 x 8192x1024 bf16 = 128 MiB @ 64 MiB
#define WS_NEEDED  53477376u
#define WS_BIG     201326592u  // 192 MiB (h1 full ends at 64+128 MiB)

__device__ __forceinline__ void async_copy16(const void* g, void* l) {
  __builtin_amdgcn_global_load_lds(
      (const __attribute__((address_space(1))) unsigned int*)g,
      (__attribute__((address_space(3))) unsigned int*)l, 16, 0, 0);
}

// ====== p99 (4-pass radix select) + valid-point compaction + zero(c) ======
// idx slot order is atomic (non-deterministic) but downstream max-pool is
// order/duplicate-invariant, so the OUTPUT is deterministic.
__global__ __launch_bounds__(1024) void k_p99(
    const float* __restrict__ pts, float* __restrict__ inv_p99,
    int* __restrict__ idx, int* __restrict__ nv, float* __restrict__ c)
{
  const int b = blockIdx.x;
  const int t = threadIdx.x;
  __shared__ unsigned int keys[NPTS];
  __shared__ int whist[16][256];
  __shared__ int hist[256];
  __shared__ int s_cnt, s_kleft;
  __shared__ unsigned int s_prefix;

  c[b*CWID + t] = 0.f;   // zero pooled-feature buffer (1024 threads == CWID)
  if (t == 0) s_cnt = 0;
  __syncthreads();

  for (int n = t; n < NPTS; n += 1024) {
    const float x = pts[(b*NPTS + n)*3 + 0];
    const float y = pts[(b*NPTS + n)*3 + 1];
    const float z = pts[(b*NPTS + n)*3 + 2];
    const bool v = x > -50.f;
    unsigned int key = 0x7F800000u;  // +inf
    if (v) {
      key = __float_as_uint(sqrtf(x*x + y*y + z*z));
      const int slot = atomicAdd(&s_cnt, 1);
      idx[b*NPTS + slot] = n;
    }
    keys[n] = key;
  }
  __syncthreads();
  if (t == 0) {
    nv[b] = s_cnt;
    s_kleft = 1 + (int)rintf(0.99f * (float)(s_cnt - 1));
    s_prefix = 0u;
  }
  __syncthreads();

  const int w = t >> 6;
  for (int pass = 0; pass < 4; ++pass) {
    const int shift = 24 - 8*pass;
    const unsigned int pref = s_prefix;
    for (int i = t; i < 16*256; i += 1024) ((int*)whist)[i] = 0;
    __syncthreads();
    for (int n = t; n < NPTS; n += 1024) {
      const unsigned int key = keys[n];
      const bool m = (pass == 0) || ((key >> (shift + 8)) == (pref >> (shift + 8)));
      if (m) atomicAdd(&whist[w][(key >> shift) & 255], 1);
    }
    __syncthreads();
    if (t < 256) { int h = 0; for (int ww = 0; ww < 16; ++ww) h += whist[ww][t]; hist[t] = h; }
    __syncthreads();
    if (t < 64) {  // wave 0: parallel scan over 256 bins (4 per lane)
      const int kl = s_kleft;
      const int s0 = hist[t*4+0], s1 = hist[t*4+1], s2 = hist[t*4+2], s3 = hist[t*4+3];
      const int sl = s0 + s1 + s2 + s3;
      int p = sl;
      #pragma unroll
      for (int o = 1; o < 64; o <<= 1) { const int v = __shfl_up(p, o); if (t >= o) p += v; }
      const unsigned long long bl = __ballot(p >= kl);
      const int L = (int)(__ffsll((unsigned long long)bl) - 1);
      if (t == L) {
        int c0 = p - sl;
        int bin = t*4;
        if (c0 + s0 < kl) { c0 += s0; ++bin;
          if (c0 + s1 < kl) { c0 += s1; ++bin;
            if (c0 + s2 < kl) { c0 += s2; ++bin; } } }
        s_prefix = pref | ((unsigned int)bin << shift);
        s_kleft = kl - c0;
      }
    }
    __syncthreads();
  }
  if (t == 0) inv_p99[b] = 1.0f / __uint_as_float(s_prefix);
}

// ========= prep: W2 -> W2^T bf16 (tiles 0..255) + W0/W1 -> wt (256..415) =========
__global__ __launch_bounds__(256) void k_prep(
    const float* __restrict__ w2, __hip_bfloat16* __restrict__ w2t,
    const float* __restrict__ W0, const float* __restrict__ W1,
    __hip_bfloat16* __restrict__ wt)
{
  __shared__ float tile[64][65];
  const int bid = blockIdx.x;
  const int t = threadIdx.x;
  const int cc = t & 63, rq = t >> 6;
  if (bid < 256) {
    const int kb = (bid >> 4) * 64, nb = (bid & 15) * 64;
    #pragma unroll
    for (int i = 0; i < 16; ++i) {
      const int r = i*4 + rq;
      tile[r][cc] = w2[(kb + r)*CWID + nb + cc];
    }
    __syncthreads();
    #pragma unroll
    for (int i = 0; i < 16; ++i) {
      const int r = i*4 + rq;
      w2t[(size_t)(nb + r)*CWID + kb + cc] = __float2bfloat16(tile[cc][r]);
    }
  } else {
    const int idx = bid - 256;
    const int s = idx >> 4;
    const int kb = ((idx >> 2) & 3) * 64, nb = (idx & 3) * 64;
    const float* src = (s < 5) ? (W0 + (size_t)s*DWID*DWID) : (W1 + (size_t)(s-5)*DWID*DWID);
    #pragma unroll
    for (int i = 0; i < 16; ++i) {
      const int r = i*4 + rq;
      tile[r][cc] = src[(kb + r)*DWID + nb + cc];
    }
    __syncthreads();
    #pragma unroll
    for (int i = 0; i < 16; ++i) {
      const int r = i*4 + rq;
      wt[(size_t)s*DWID*DWID + (size_t)(nb + r)*DWID + kb + cc] = __float2bfloat16(tile[cc][r]);
    }
  }
}

// == encoder layer 1 (compacted rows, 16 rows/block) -> h1 bf16, 16B stores ==
#define E1R 16
__global__ __launch_bounds__(256) void k_enc1(
    const float* __restrict__ pts, const float* __restrict__ rgb,
    const float* __restrict__ inv_p99, const int* __restrict__ idx,
    const int* __restrict__ nv,
    const float* __restrict__ W1, const float* __restrict__ b1,
    __hip_bfloat16* __restrict__ h1, int b0)
{
  __shared__ float xs[E1R][6];
  const int z = blockIdx.y;
  const int b = b0 + z;
  const int nvb = nv[b];
  const int r0 = blockIdx.x * E1R;
  if (r0 >= ((nvb + 127) & ~127)) return;
  const int t = threadIdx.x;
  __hip_bfloat16* dst = h1 + (size_t)z*NPTS*CWID;
  if (t < E1R*6) {
    const int m = t / 6, j = t % 6;
    const int row = r0 + m;
    float val = 0.f;
    if (row < nvb) {
      const int gi = b*NPTS + idx[b*NPTS + row];
      const float inv = inv_p99[b];
      val = (j < 3) ? pts[gi*3 + j] * inv : rgb[gi*3 + j - 3];
    }
    xs[m][j] = val;
  }
  __syncthreads();
  #pragma unroll
  for (int k = 0; k < E1R/2; ++k) {
    const int ci = k*256 + t;
    const int m = ci >> 7;           // 0..E1R-1
    const bool vrow = (r0 + m) < nvb;
    const int coff = (ci & 127) * 8; // 8 cols per chunk
    const float x0 = xs[m][0], x1 = xs[m][1], x2 = xs[m][2];
    const float x3 = xs[m][3], x4 = xs[m][4], x5 = xs[m][5];
    f32x4 aA = *reinterpret_cast<const f32x4*>(&b1[coff]);
    f32x4 aB = *reinterpret_cast<const f32x4*>(&b1[coff + 4]);
    aA = aA + *reinterpret_cast<const f32x4*>(&W1[0*CWID + coff]) * x0;
    aB = aB + *reinterpret_cast<const f32x4*>(&W1[0*CWID + coff + 4]) * x0;
    aA = aA + *reinterpret_cast<const f32x4*>(&W1[1*CWID + coff]) * x1;
    aB = aB + *reinterpret_cast<const f32x4*>(&W1[1*CWID + coff + 4]) * x1;
    aA = aA + *reinterpret_cast<const f32x4*>(&W1[2*CWID + coff]) * x2;
    aB = aB + *reinterpret_cast<const f32x4*>(&W1[2*CWID + coff + 4]) * x2;
    aA = aA + *reinterpret_cast<const f32x4*>(&W1[3*CWID + coff]) * x3;
    aB = aB + *reinterpret_cast<const f32x4*>(&W1[3*CWID + coff + 4]) * x3;
    aA = aA + *reinterpret_cast<const f32x4*>(&W1[4*CWID + coff]) * x4;
    aB = aB + *reinterpret_cast<const f32x4*>(&W1[4*CWID + coff + 4]) * x4;
    aA = aA + *reinterpret_cast<const f32x4*>(&W1[5*CWID + coff]) * x5;
    aB = aB + *reinterpret_cast<const f32x4*>(&W1[5*CWID + coff + 4]) * x5;
    bf16x8 pk;
    #pragma unroll
    for (int u = 0; u < 4; ++u) pk[u]   = vrow ? (__bf16)fmaxf(aA[u], 0.f) : (__bf16)0.f;
    #pragma unroll
    for (int u = 0; u < 4; ++u) pk[4+u] = vrow ? (__bf16)fmaxf(aB[u], 0.f) : (__bf16)0.f;
    *reinterpret_cast<bf16x8*>(&dst[(size_t)(r0 + m)*CWID + coff]) = pk;
  }
}

// ===== encoder layer 2: 128x256 tile, 8 waves, octet-swizzled LDS + max-pool =====
// LDS layout: 16B unit (row, logical octet ao) at addr16 = row*8 + (ao ^ (row&7)).
// (Round-15 proven structure: 104.7 us, 920 TF. B-direct-from-L2 variant was
//  2.5x WORSE — L2 latency on the MFMA critical path; keep LDS staging.)
#define EBM 128
#define EBN 256
#define EBK 64

__global__ __launch_bounds__(512) void k_enc2(
    const __hip_bfloat16* __restrict__ h1,   // [nz][8192][1024] compacted rows
    const __hip_bfloat16* __restrict__ w2t,  // [1024][1024] n-major
    const float* __restrict__ b2,
    const int* __restrict__ nv,
    float* __restrict__ c, int b0)           // [NB][CWID]
{
  __shared__ __align__(16) __hip_bfloat16 As[EBM*EBK];   // 16 KB
  __shared__ __align__(16) __hip_bfloat16 Bs[EBN*EBK];   // 32 KB
  const int t = threadIdx.x;
  const int lane = t & 63, wid = t >> 6;
  const int wm = wid >> 2, wn = wid & 3;     // 2 x 4 wave grid
  const int m0 = blockIdx.x * EBM;
  const int n0 = blockIdx.y * EBN;
  const int z  = blockIdx.z;
  const int b  = b0 + z;
  const int nvb = nv[b];
  if (m0 >= ((nvb + 127) & ~127)) return;   // whole tile is padding: skip
  const __hip_bfloat16* h1b = h1 + (size_t)z*NPTS*CWID;

  f32x4 acc[4][4] = {};

  for (int kt = 0; kt < 16; ++kt) {
    {
      const int k0_ = kt*EBK;
      // A: 1024 16B-units, 2 per thread
      #pragma unroll
      for (int qq = 0; qq < 2; ++qq) {
        const int cib = qq*512 + wid*64;     // wave-uniform dest base
        const int ci  = cib + lane;
        const int rw  = ci >> 3;
        const int oct = (ci & 7) ^ (rw & 7);
        async_copy16(h1b + (size_t)(m0 + rw)*CWID + k0_ + oct*8,
                     (__hip_bfloat16*)As + cib*8);
      }
      // B: 2048 16B-units, 4 per thread
      #pragma unroll
      for (int qq = 0; qq < 4; ++qq) {
        const int cib = qq*512 + wid*64;
        const int ci  = cib + lane;
        const int rw  = ci >> 3;
        const int oct = (ci & 7) ^ (rw & 7);
        async_copy16(w2t + (size_t)(n0 + rw)*CWID + k0_ + oct*8,
                     (__hip_bfloat16*)Bs + cib*8);
      }
    }
    __syncthreads();   // drains global_load_lds (vmcnt) + barrier: buffer ready
    #pragma unroll
    for (int ks = 0; ks < 2; ++ks) {
      const int ke = ks*32 + (lane >> 4)*8;
      const int ao = ke >> 3;
      bf16x8 a[4], bfr[4];
      #pragma unroll
      for (int f = 0; f < 4; ++f) {
        const int ar = wm*64 + f*16 + (lane & 15);
        const int br = wn*64 + f*16 + (lane & 15);
        a[f]   = *reinterpret_cast<const bf16x8*>((char*)As + (ar*8 + (ao ^ (ar & 7)))*16);
        bfr[f] = *reinterpret_cast<const bf16x8*>((char*)Bs + (br*8 + (ao ^ (br & 7)))*16);
      }
      #pragma unroll
      for (int fm = 0; fm < 4; ++fm)
        #pragma unroll
        for (int fn = 0; fn < 4; ++fn)
          acc[fm][fn] = __builtin_amdgcn_mfma_f32_16x16x32_bf16(a[fm], bfr[fn], acc[fm][fn], 0, 0, 0);
    }
    __syncthreads();   // all readers done before next STAGE overwrites
  }

  // epilogue: bias + relu + max over compacted rows (< nvb) -> atomicMax into c
  const int rbase = (lane >> 4)*4;
  #pragma unroll
  for (int fn = 0; fn < 4; ++fn) {
    const int gn = n0 + wn*64 + fn*16 + (lane & 15);
    const float bv = b2[gn];
    float mx = 0.f;
    #pragma unroll
    for (int fm = 0; fm < 4; ++fm) {
      const int gmb = m0 + wm*64 + fm*16 + rbase;
      #pragma unroll
      for (int r = 0; r < 4; ++r) {
        const float v = fmaxf(acc[fm][fn][r] + bv, 0.f);
        if (gmb + r < nvb) mx = fmaxf(mx, v);
      }
    }
    mx = fmaxf(mx, __shfl_xor(mx, 16));
    mx = fmaxf(mx, __shfl_xor(mx, 32));
    if ((lane >> 4) == 0)
      atomicMax((int*)(c + b*CWID + gn), __float_as_int(mx));  // values >= 0
  }
}

// ================= gamma/beta: stage A (split-K partials) =================
__global__ __launch_bounds__(256) void k_gbp(
    const float* __restrict__ c,
    const float* __restrict__ Wg0, const float* __restrict__ Wb0,
    const float* __restrict__ Wg1, const float* __restrict__ Wb1,
    const float* __restrict__ bnWg, const float* __restrict__ bnWb,
    float* __restrict__ gbp)
{
  __shared__ float cs[8][64];
  __shared__ float red[4][8][256];
  const int s  = blockIdx.y;
  const int kc = blockIdx.x;
  const int k0 = kc * 64;
  const int t  = threadIdx.x;

  const float* W;
  if      (s < 5)  W = Wg0 + (size_t)s*CWID*DWID;
  else if (s < 10) W = Wb0 + (size_t)(s-5)*CWID*DWID;
  else if (s < 15) W = Wg1 + (size_t)(s-10)*CWID*DWID;
  else if (s < 20) W = Wb1 + (size_t)(s-15)*CWID*DWID;
  else if (s == 20) W = bnWg;
  else              W = bnWb;

  {
    const int i0 = t*2;
    cs[i0 >> 6][i0 & 63]         = c[(i0 >> 6)*CWID + k0 + (i0 & 63)];
    cs[(i0+1) >> 6][(i0+1) & 63] = c[((i0+1) >> 6)*CWID + k0 + ((i0+1) & 63)];
  }
  __syncthreads();

  const int sub = t >> 6;
  const int c0  = (t & 63) * 4;
  f32x4 acc[8] = {};
  #pragma unroll
  for (int i = 0; i < 16; ++i) {
    const int kk = sub*16 + i;
    const f32x4 w = *reinterpret_cast<const f32x4*>(&W[(size_t)(k0 + kk)*DWID + c0]);
    #pragma unroll
    for (int b = 0; b < 8; ++b) acc[b] = acc[b] + w * cs[b][kk];
  }
  #pragma unroll
  for (int b = 0; b < 8; ++b)
    *reinterpret_cast<f32x4*>(&red[sub][b][c0]) = acc[b];
  __syncthreads();
  for (int b = 0; b < 8; ++b) {
    const float v = red[0][b][t] + red[1][b][t] + red[2][b][t] + red[3][b][t];
    gbp[(((size_t)s*16 + kc)*8 + b)*DWID + t] = v;
  }
}

// ================= gamma/beta: stage B (reduce + bias) =================
__global__ __launch_bounds__(256) void k_gbf(
    const float* __restrict__ gbp,
    const float* __restrict__ bg0, const float* __restrict__ bb0,
    const float* __restrict__ bg1, const float* __restrict__ bb1,
    const float* __restrict__ bnbg, const float* __restrict__ bnbb,
    float* __restrict__ gb)
{
  const int s = blockIdx.x;
  const int t = threadIdx.x;
  const float* bias;
  if      (s < 5)  bias = bg0 + s*DWID;
  else if (s < 10) bias = bb0 + (s-5)*DWID;
  else if (s < 15) bias = bg1 + (s-10)*DWID;
  else if (s < 20) bias = bb1 + (s-15)*DWID;
  else if (s == 20) bias = bnbg;
  else              bias = bnbb;
  const float bv = bias[t];
  for (int b = 0; b < 8; ++b) {
    float acc = bv;
    #pragma unroll
    for (int kc = 0; kc < 16; ++kc)
      acc += gbp[(((size_t)s*16 + kc)*8 + b)*DWID + t];
    gb[((size_t)s*8 + b)*DWID + t] = acc;
  }
}

// ================= fc_p (64 rows/block) + stat partials =================
__global__ __launch_bounds__(256) void k_fcp2(
    const float* __restrict__ qc, const float* __restrict__ inv_p99,
    const float* __restrict__ W, const float* __restrict__ bias,
    float* __restrict__ net, float* __restrict__ part)
{
  __shared__ float qs[192];
  const int blk = blockIdx.x;
  const int r0 = blk * 64;
  const int b = r0 >> 11;
  const int t = threadIdx.x;
  if (t < 192) qs[t] = qc[(size_t)r0*3 + t] * inv_p99[b];
  __syncthreads();
  const float w0 = W[t], w1 = W[DWID + t], w2 = W[2*DWID + t];
  const float bv = bias[t];
  float s = 0.f, q = 0.f;
  for (int m = 0; m < 64; ++m) {
    const float v = bv + qs[m*3]*w0 + qs[m*3+1]*w1 + qs[m*3+2]*w2;
    net[(size_t)(r0 + m)*DWID + t] = v;
    s += v; q += v*v;
  }
  part[(size_t)t*NPBLK + blk] = s;
  part[(size_t)(256 + t)*NPBLK + blk] = q;
}

// ====== stats finalize (32 blocks x 8 cols; contiguous col-major reads) ======
__global__ __launch_bounds__(256) void k_statf(
    const float* __restrict__ part, float* __restrict__ stats)
{
  const int t = threadIdx.x;
  const int j = t >> 5;            // col within block (0..7)
  const int lane = t & 31;
  const int col = blockIdx.x * 8 + j;
  const float* ps = part + (size_t)col*NPBLK;
  const float* pq = part + (size_t)(256 + col)*NPBLK;
  f32x4 sv = {}, qv = {};
  #pragma unroll
  for (int i = 0; i < 2; ++i) {
    sv = sv + *reinterpret_cast<const f32x4*>(ps + i*128 + lane*4);
    qv = qv + *reinterpret_cast<const f32x4*>(pq + i*128 + lane*4);
  }
  float s = (sv[0]+sv[1]) + (sv[2]+sv[3]);
  float q = (qv[0]+qv[1]) + (qv[2]+qv[3]);
  #pragma unroll
  for (int o = 16; o > 0; o >>= 1) { s += __shfl_down(s, o); q += __shfl_down(q, o); }
  if (lane == 0) {
    const float mean = s * (1.f/16384.f);
    const float var  = q * (1.f/16384.f) - mean*mean;
    stats[col] = mean;
    stats[256 + col] = rsqrtf(var + 1e-5f);
  }
}

// ========== CBN + relu + MFMA matmul (+residual) + stat partials ==========
// 64 rows/block: each block reads wt once (halved L2 traffic vs 32-row).
__global__ __launch_bounds__(256) void k_cbnmm(
    const float* __restrict__ X, const float* __restrict__ stats,
    const float* __restrict__ gb, int gslot, int bslot,
    const __hip_bfloat16* __restrict__ wt,   // [256 n][256 k] bf16
    const float* __restrict__ bias,
    float* __restrict__ out, int addmode, float* __restrict__ part)
{
  __shared__ __align__(16) __hip_bfloat16 xs[64 * 256];  // swizzled [row][k], 32 KB
  __shared__ float sred[4][2][128];
  const int t = threadIdx.x;
  const int blk = blockIdx.x;
  const int r0 = blk * 64;
  const int bb = r0 >> 11;

  // ---- stage: CBN + relu + bf16, XOR-swizzled on 16B groups ----
  {
    const int cq = (t & 63) * 4;
    const f32x4 mn = *reinterpret_cast<const f32x4*>(&stats[cq]);
    const f32x4 rs = *reinterpret_cast<const f32x4*>(&stats[256 + cq]);
    const f32x4 g  = *reinterpret_cast<const f32x4*>(&gb[((size_t)gslot*8 + bb)*DWID + cq]);
    const f32x4 be = *reinterpret_cast<const f32x4*>(&gb[((size_t)bslot*8 + bb)*DWID + cq]);
    const int rbase = t >> 6;
    #pragma unroll
    for (int j = 0; j < 16; ++j) {
      const int r = rbase + j*4;
      const f32x4 v = *reinterpret_cast<const f32x4*>(&X[(size_t)(r0 + r)*DWID + cq]);
      bf16x4 h;
      #pragma unroll
      for (int jj = 0; jj < 4; ++jj)
        h[jj] = (__bf16)fmaxf(0.f, (v[jj] - mn[jj])*rs[jj]*g[jj] + be[jj]);
      const int grp = (cq >> 3) ^ (r & 7);
      *reinterpret_cast<bf16x4*>((char*)xs + r*512 + grp*16 + (cq & 7)*2) = h;
    }
  }
  __syncthreads();

  const int lane = t & 63, wid = t >> 6;
  const int wm = wid >> 1, wn = wid & 1;
  f32x4 acc[2][8] = {};
  #pragma unroll
  for (int kstep = 0; kstep < 8; ++kstep) {
    const int ke = kstep*32 + (lane >> 4)*8;
    bf16x8 a[2], bfr[8];
    #pragma unroll
    for (int fm = 0; fm < 2; ++fm) {
      const int row = wm*32 + fm*16 + (lane & 15);
      a[fm] = *reinterpret_cast<const bf16x8*>(
          (char*)xs + row*512 + (((ke >> 3) ^ (row & 7))*16));
    }
    #pragma unroll
    for (int fn = 0; fn < 8; ++fn) {
      const int n = wn*128 + fn*16 + (lane & 15);
      bfr[fn] = *reinterpret_cast<const bf16x8*>(&wt[(size_t)n*DWID + ke]);
    }
    #pragma unroll
    for (int fm = 0; fm < 2; ++fm)
      #pragma unroll
      for (int fn = 0; fn < 8; ++fn)
        acc[fm][fn] = __builtin_amdgcn_mfma_f32_16x16x32_bf16(a[fm], bfr[fn], acc[fm][fn], 0, 0, 0);
  }

  // ---- epilogue: bias + residual + store + per-block column sums ----
  const int rb = (lane >> 4) * 4;
  #pragma unroll
  for (int fn = 0; fn < 8; ++fn) {
    const int gn = wn*128 + fn*16 + (lane & 15);
    const float bv = bias[gn];
    float s = 0.f, q = 0.f;
    #pragma unroll
    for (int fm = 0; fm < 2; ++fm) {
      const size_t row0 = (size_t)r0 + wm*32 + fm*16 + rb;
      #pragma unroll
      for (int r = 0; r < 4; ++r) {
        float v = acc[fm][fn][r] + bv;
        if (addmode) v += out[(row0 + r)*DWID + gn];
        out[(row0 + r)*DWID + gn] = v;
        s += v; q += v*v;
      }
    }
    s += __shfl_xor(s, 16); s += __shfl_xor(s, 32);
    q += __shfl_xor(q, 16); q += __shfl_xor(q, 32);
    if ((lane >> 4) == 0) {
      sred[wid][0][fn*16 + (lane & 15)] = s;
      sred[wid][1][fn*16 + (lane & 15)] = q;
    }
  }
  __syncthreads();
  {
    const int col = t;           // 0..255
    const int wn2 = col >> 7, cl = col & 127;
    const float s = sred[wn2][0][cl] + sred[2 + wn2][0][cl];
    const float q = sred[wn2][1][cl] + sred[2 + wn2][1][cl];
    part[(size_t)col*NPBLK + blk] = s;
    part[(size_t)(256 + col)*NPBLK + blk] = q;
  }
}

// ================= final CBN + relu + fc_out =================
__global__ __launch_bounds__(256) void k_final(
    const float* __restrict__ net, const float* __restrict__ stats,
    const float* __restrict__ gb, const float* __restrict__ fcW,
    const float* __restrict__ fcb, float* __restrict__ out)
{
  const int wid = threadIdx.x >> 6, lane = threadIdx.x & 63;
  const int m = blockIdx.x*4 + wid;
  const int b = m >> 11;
  const int f0 = lane*4;
  const f32x4 x  = *reinterpret_cast<const f32x4*>(&net[(size_t)m*DWID + f0]);
  const f32x4 mn = *reinterpret_cast<const f32x4*>(&stats[f0]);
  const f32x4 rs = *reinterpret_cast<const f32x4*>(&stats[256 + f0]);
  const f32x4 g  = *reinterpret_cast<const f32x4*>(&gb[(20*8 + (size_t)b)*DWID + f0]);
  const f32x4 be = *reinterpret_cast<const f32x4*>(&gb[(21*8 + (size_t)b)*DWID + f0]);
  const f32x4 w  = *reinterpret_cast<const f32x4*>(&fcW[f0]);
  float s = 0.f;
  #pragma unroll
  for (int j = 0; j < 4; ++j)
    s += fmaxf(0.f, (x[j] - mn[j])*rs[j]*g[j] + be[j]) * w[j];
  #pragma unroll
  for (int o = 32; o > 0; o >>= 1) s += __shfl_down(s, o);
  if (lane == 0) out[m] = s + fcb[0];
}

// ================= launch =================
extern "C" void kernel_launch(void* const* d_in, const int* in_sizes, int n_in,
                              void* d_out, int out_size, void* d_ws, size_t ws_size,
                              hipStream_t stream) {
  (void)in_sizes; (void)n_in; (void)out_size;
  if (ws_size < WS_NEEDED) return;

  const float* pts    = (const float*)d_in[0];
  const float* rgb    = (const float*)d_in[1];
  const float* qc     = (const float*)d_in[2];
  const float* enc_W1 = (const float*)d_in[3];
  const float* enc_b1 = (const float*)d_in[4];
  const float* enc_W2 = (const float*)d_in[5];
  const float* enc_b2 = (const float*)d_in[6];
  const float* fc_p_W = (const float*)d_in[7];
  const float* fc_p_b = (const float*)d_in[8];
  const float* Wg0 = (const float*)d_in[9];
  const float* bg0 = (const float*)d_in[10];
  const float* Wb0 = (const float*)d_in[11];
  const float* bb0 = (const float*)d_in[12];
  const float* W0  = (const float*)d_in[13];
  const float* b0  = (const float*)d_in[14];
  const float* Wg1 = (const float*)d_in[15];
  const float* bg1 = (const float*)d_in[16];
  const float* Wb1 = (const float*)d_in[17];
  const float* bb1 = (const float*)d_in[18];
  const float* W1  = (const float*)d_in[19];
  const float* b1  = (const float*)d_in[20];
  const float* bnWg = (const float*)d_in[21];
  const float* bnbg = (const float*)d_in[22];
  const float* bnWb = (const float*)d_in[23];
  const float* bnbb = (const float*)d_in[24];
  const float* fcoW = (const float*)d_in[25];
  const float* fcob = (const float*)d_in[26];
  float* out = (float*)d_out;

  char* ws = (char*)d_ws;
  float* inv_p99 = (float*)(ws + OFF_INV);
  float* c      = (float*)(ws + OFF_C);
  float* gbuf   = (float*)(ws + OFF_GB);
  float* stats  = (float*)(ws + OFF_STATS);
  __hip_bfloat16* w2t = (__hip_bfloat16*)(ws + OFF_W2T);
  __hip_bfloat16* wt  = (__hip_bfloat16*)(ws + OFF_WT);
  float* gbp  = (float*)(ws + OFF_GBP);
  float* part = (float*)(ws + OFF_PART);
  int*   idx  = (int*)(ws + OFF_IDX);
  int*   nvp  = (int*)(ws + OFF_NV);
  float* net = (float*)(ws + OFF_NET);
  float* dx  = (float*)(ws + OFF_DX);

  k_p99<<<NB, 1024, 0, stream>>>(pts, inv_p99, idx, nvp, c);
  k_prep<<<416, 256, 0, stream>>>(enc_W2, w2t, W0, W1, wt);

  if (ws_size >= WS_BIG) {
    // big path: full h1 at 64 MiB, single encoder launch over all 8 batches
    __hip_bfloat16* h1f = (__hip_bfloat16*)(ws + OFF_H1F);
    k_enc1<<<dim3(NPTS/E1R, NB), 256, 0, stream>>>(pts, rgb, inv_p99, idx, nvp,
                                                   enc_W1, enc_b1, h1f, 0);
    k_enc2<<<dim3(NPTS/EBM, CWID/EBN, NB), 512, 0, stream>>>(h1f, w2t, enc_b2,
                                                             nvp, c, 0);
  } else {
    // fallback: pair-looped encoder, h1 aliases net/dx
    __hip_bfloat16* h1 = (__hip_bfloat16*)(ws + OFF_H1);
    for (int bp = 0; bp < 4; ++bp) {
      k_enc1<<<dim3(NPTS/E1R, 2), 256, 0, stream>>>(pts, rgb, inv_p99, idx, nvp,
                                                    enc_W1, enc_b1, h1, bp*2);
      k_enc2<<<dim3(NPTS/EBM, CWID/EBN, 2), 512, 0, stream>>>(h1, w2t, enc_b2,
                                                              nvp, c, bp*2);
    }
  }

  k_gbp<<<dim3(16,22), 256, 0, stream>>>(c, Wg0, Wb0, Wg1, Wb1, bnWg, bnWb, gbp);
  k_gbf<<<22, 256, 0, stream>>>(gbp, bg0, bb0, bg1, bb1, bnbg, bnbb, gbuf);

  k_fcp2<<<NPBLK, 256, 0, stream>>>(qc, inv_p99, fc_p_W, fc_p_b, net, part);
  k_statf<<<32, 256, 0, stream>>>(part, stats);
  for (int i = 0; i < 5; ++i) {
    k_cbnmm<<<NPBLK, 256, 0, stream>>>(net, stats, gbuf, i, 5+i,
                                       wt + (size_t)i*DWID*DWID, b0 + i*DWID, dx, 0, part);
    k_statf<<<32, 256, 0, stream>>>(part, stats);
    k_cbnmm<<<NPBLK, 256, 0, stream>>>(dx, stats, gbuf, 10+i, 15+i,
                                       wt + (size_t)(5+i)*DWID*DWID, b1 + i*DWID, net, 1, part);
    k_statf<<<32, 256, 0, stream>>>(part, stats);
  }
  k_final<<<NB*NT/4, 256, 0, stream>>>(net, stats, gbuf, fcoW, fcob, out);
}

// Round 19
// 406.052 us; speedup vs baseline: 1.4832x; 1.0890x over previous
//
#include <hip/hip_runtime.h>
#include <hip/hip_bf16.h>

#define NB   8
#define NPTS 8192
#define NT   2048
#define CWID 1024
#define DWID 256
#define NPBLK 256   // stat-partial blocks per stage

using f32x4  = __attribute__((ext_vector_type(4))) float;
using bf16x8 = __attribute__((ext_vector_type(8))) __bf16;
using bf16x4 = __attribute__((ext_vector_type(4))) __bf16;

// ---------------- ws layout (bytes) ----------------
#define OFF_INV    0u          // 8 f32 inv_p99
#define OFF_C      66560u      // 8x1024 f32
#define OFF_GB     99328u      // 22x8x256 f32 gamma/beta
#define OFF_STATS  279552u     // 512 f32 stats
#define OFF_W2T    1048576u    // 1024x1024 bf16 (W2 transposed)
#define OFF_WT     3145728u    // 10x256x256 bf16 (decoder W, n-major)
#define OFF_GBP    4456448u    // 22x16x8x256 f32 gb partials
#define OFF_PART   7340032u    // [512 cols][256 blocks] f32 stat partials (col-major)
#define OFF_IDX    8388608u    // 8x8192 i32 compacted valid-point indices
#define OFF_NV     8650752u    // 8 i32 valid counts
#define OFF_NET    19922944u   // 16384x256 bf16 (aliases h1 during encoder, small path)
#define OFF_DX     36700160u   // 16384x256 bf16
#define OFF_H1     19922944u   // small path: 2 x 8192x1024 bf16 = 32 MB (dead before fcp2)
#define OFF_H1F    67108864u   // big path: 8 x 8192x1024 bf16 = 128 MiB @ 64 MiB
#define WS_NEEDED  53477376u
#define WS_BIG     201326592u  // 192 MiB (h1 full ends at 64+128 MiB)

__device__ __forceinline__ void async_copy16(const void* g, void* l) {
  __builtin_amdgcn_global_load_lds(
      (const __attribute__((address_space(1))) unsigned int*)g,
      (__attribute__((address_space(3))) unsigned int*)l, 16, 0, 0);
}

// ====== p99 (4-pass radix select) + valid-point compaction + zero(c) ======
// idx slot order is atomic (non-deterministic) but downstream max-pool is
// order/duplicate-invariant, so the OUTPUT is deterministic.
__global__ __launch_bounds__(1024) void k_p99(
    const float* __restrict__ pts, float* __restrict__ inv_p99,
    int* __restrict__ idx, int* __restrict__ nv, float* __restrict__ c)
{
  const int b = blockIdx.x;
  const int t = threadIdx.x;
  __shared__ unsigned int keys[NPTS];
  __shared__ int whist[16][256];
  __shared__ int hist[256];
  __shared__ int s_cnt, s_kleft;
  __shared__ unsigned int s_prefix;

  c[b*CWID + t] = 0.f;   // zero pooled-feature buffer (1024 threads == CWID)
  if (t == 0) s_cnt = 0;
  __syncthreads();

  for (int n = t; n < NPTS; n += 1024) {
    const float x = pts[(b*NPTS + n)*3 + 0];
    const float y = pts[(b*NPTS + n)*3 + 1];
    const float z = pts[(b*NPTS + n)*3 + 2];
    const bool v = x > -50.f;
    unsigned int key = 0x7F800000u;  // +inf
    if (v) {
      key = __float_as_uint(sqrtf(x*x + y*y + z*z));
      const int slot = atomicAdd(&s_cnt, 1);
      idx[b*NPTS + slot] = n;
    }
    keys[n] = key;
  }
  __syncthreads();
  if (t == 0) {
    nv[b] = s_cnt;
    s_kleft = 1 + (int)rintf(0.99f * (float)(s_cnt - 1));
    s_prefix = 0u;
  }
  __syncthreads();

  const int w = t >> 6;
  for (int pass = 0; pass < 4; ++pass) {
    const int shift = 24 - 8*pass;
    const unsigned int pref = s_prefix;
    for (int i = t; i < 16*256; i += 1024) ((int*)whist)[i] = 0;
    __syncthreads();
    for (int n = t; n < NPTS; n += 1024) {
      const unsigned int key = keys[n];
      const bool m = (pass == 0) || ((key >> (shift + 8)) == (pref >> (shift + 8)));
      if (m) atomicAdd(&whist[w][(key >> shift) & 255], 1);
    }
    __syncthreads();
    if (t < 256) { int h = 0; for (int ww = 0; ww < 16; ++ww) h += whist[ww][t]; hist[t] = h; }
    __syncthreads();
    if (t < 64) {  // wave 0: parallel scan over 256 bins (4 per lane)
      const int kl = s_kleft;
      const int s0 = hist[t*4+0], s1 = hist[t*4+1], s2 = hist[t*4+2], s3 = hist[t*4+3];
      const int sl = s0 + s1 + s2 + s3;
      int p = sl;
      #pragma unroll
      for (int o = 1; o < 64; o <<= 1) { const int v = __shfl_up(p, o); if (t >= o) p += v; }
      const unsigned long long bl = __ballot(p >= kl);
      const int L = (int)(__ffsll((unsigned long long)bl) - 1);
      if (t == L) {
        int c0 = p - sl;
        int bin = t*4;
        if (c0 + s0 < kl) { c0 += s0; ++bin;
          if (c0 + s1 < kl) { c0 += s1; ++bin;
            if (c0 + s2 < kl) { c0 += s2; ++bin; } } }
        s_prefix = pref | ((unsigned int)bin << shift);
        s_kleft = kl - c0;
      }
    }
    __syncthreads();
  }
  if (t == 0) inv_p99[b] = 1.0f / __uint_as_float(s_prefix);
}

// ========= prep: W2 -> W2^T bf16 (tiles 0..255) + W0/W1 -> wt (256..415) =========
__global__ __launch_bounds__(256) void k_prep(
    const float* __restrict__ w2, __hip_bfloat16* __restrict__ w2t,
    const float* __restrict__ W0, const float* __restrict__ W1,
    __hip_bfloat16* __restrict__ wt)
{
  __shared__ float tile[64][65];
  const int bid = blockIdx.x;
  const int t = threadIdx.x;
  const int cc = t & 63, rq = t >> 6;
  if (bid < 256) {
    const int kb = (bid >> 4) * 64, nb = (bid & 15) * 64;
    #pragma unroll
    for (int i = 0; i < 16; ++i) {
      const int r = i*4 + rq;
      tile[r][cc] = w2[(kb + r)*CWID + nb + cc];
    }
    __syncthreads();
    #pragma unroll
    for (int i = 0; i < 16; ++i) {
      const int r = i*4 + rq;
      w2t[(size_t)(nb + r)*CWID + kb + cc] = __float2bfloat16(tile[cc][r]);
    }
  } else {
    const int idx = bid - 256;
    const int s = idx >> 4;
    const int kb = ((idx >> 2) & 3) * 64, nb = (idx & 3) * 64;
    const float* src = (s < 5) ? (W0 + (size_t)s*DWID*DWID) : (W1 + (size_t)(s-5)*DWID*DWID);
    #pragma unroll
    for (int i = 0; i < 16; ++i) {
      const int r = i*4 + rq;
      tile[r][cc] = src[(kb + r)*DWID + nb + cc];
    }
    __syncthreads();
    #pragma unroll
    for (int i = 0; i < 16; ++i) {
      const int r = i*4 + rq;
      wt[(size_t)s*DWID*DWID + (size_t)(nb + r)*DWID + kb + cc] = __float2bfloat16(tile[cc][r]);
    }
  }
}

// == encoder layer 1 (compacted rows, 16 rows/block) -> h1 bf16, 16B stores ==
#define E1R 16
__global__ __launch_bounds__(256) void k_enc1(
    const float* __restrict__ pts, const float* __restrict__ rgb,
    const float* __restrict__ inv_p99, const int* __restrict__ idx,
    const int* __restrict__ nv,
    const float* __restrict__ W1, const float* __restrict__ b1,
    __hip_bfloat16* __restrict__ h1, int b0)
{
  __shared__ float xs[E1R][6];
  const int z = blockIdx.y;
  const int b = b0 + z;
  const int nvb = nv[b];
  const int r0 = blockIdx.x * E1R;
  if (r0 >= ((nvb + 127) & ~127)) return;
  const int t = threadIdx.x;
  __hip_bfloat16* dst = h1 + (size_t)z*NPTS*CWID;
  if (t < E1R*6) {
    const int m = t / 6, j = t % 6;
    const int row = r0 + m;
    float val = 0.f;
    if (row < nvb) {
      const int gi = b*NPTS + idx[b*NPTS + row];
      const float inv = inv_p99[b];
      val = (j < 3) ? pts[gi*3 + j] * inv : rgb[gi*3 + j - 3];
    }
    xs[m][j] = val;
  }
  __syncthreads();
  #pragma unroll
  for (int k = 0; k < E1R/2; ++k) {
    const int ci = k*256 + t;
    const int m = ci >> 7;           // 0..E1R-1
    const bool vrow = (r0 + m) < nvb;
    const int coff = (ci & 127) * 8; // 8 cols per chunk
    const float x0 = xs[m][0], x1 = xs[m][1], x2 = xs[m][2];
    const float x3 = xs[m][3], x4 = xs[m][4], x5 = xs[m][5];
    f32x4 aA = *reinterpret_cast<const f32x4*>(&b1[coff]);
    f32x4 aB = *reinterpret_cast<const f32x4*>(&b1[coff + 4]);
    aA = aA + *reinterpret_cast<const f32x4*>(&W1[0*CWID + coff]) * x0;
    aB = aB + *reinterpret_cast<const f32x4*>(&W1[0*CWID + coff + 4]) * x0;
    aA = aA + *reinterpret_cast<const f32x4*>(&W1[1*CWID + coff]) * x1;
    aB = aB + *reinterpret_cast<const f32x4*>(&W1[1*CWID + coff + 4]) * x1;
    aA = aA + *reinterpret_cast<const f32x4*>(&W1[2*CWID + coff]) * x2;
    aB = aB + *reinterpret_cast<const f32x4*>(&W1[2*CWID + coff + 4]) * x2;
    aA = aA + *reinterpret_cast<const f32x4*>(&W1[3*CWID + coff]) * x3;
    aB = aB + *reinterpret_cast<const f32x4*>(&W1[3*CWID + coff + 4]) * x3;
    aA = aA + *reinterpret_cast<const f32x4*>(&W1[4*CWID + coff]) * x4;
    aB = aB + *reinterpret_cast<const f32x4*>(&W1[4*CWID + coff + 4]) * x4;
    aA = aA + *reinterpret_cast<const f32x4*>(&W1[5*CWID + coff]) * x5;
    aB = aB + *reinterpret_cast<const f32x4*>(&W1[5*CWID + coff + 4]) * x5;
    bf16x8 pk;
    #pragma unroll
    for (int u = 0; u < 4; ++u) pk[u]   = vrow ? (__bf16)fmaxf(aA[u], 0.f) : (__bf16)0.f;
    #pragma unroll
    for (int u = 0; u < 4; ++u) pk[4+u] = vrow ? (__bf16)fmaxf(aB[u], 0.f) : (__bf16)0.f;
    *reinterpret_cast<bf16x8*>(&dst[(size_t)(r0 + m)*CWID + coff]) = pk;
  }
}

// ===== encoder layer 2: 128x256 tile, 8 waves, octet-swizzled LDS + max-pool =====
// LDS layout: 16B unit (row, logical octet ao) at addr16 = row*8 + (ao ^ (row&7)).
// (Proven structure: 104.7 us, 920 TF. B-direct-from-L2 variant was 2.5x WORSE.)
#define EBM 128
#define EBN 256
#define EBK 64

__global__ __launch_bounds__(512) void k_enc2(
    const __hip_bfloat16* __restrict__ h1,   // [nz][8192][1024] compacted rows
    const __hip_bfloat16* __restrict__ w2t,  // [1024][1024] n-major
    const float* __restrict__ b2,
    const int* __restrict__ nv,
    float* __restrict__ c, int b0)           // [NB][CWID]
{
  __shared__ __align__(16) __hip_bfloat16 As[EBM*EBK];   // 16 KB
  __shared__ __align__(16) __hip_bfloat16 Bs[EBN*EBK];   // 32 KB
  const int t = threadIdx.x;
  const int lane = t & 63, wid = t >> 6;
  const int wm = wid >> 2, wn = wid & 3;     // 2 x 4 wave grid
  const int m0 = blockIdx.x * EBM;
  const int n0 = blockIdx.y * EBN;
  const int z  = blockIdx.z;
  const int b  = b0 + z;
  const int nvb = nv[b];
  if (m0 >= ((nvb + 127) & ~127)) return;   // whole tile is padding: skip
  const __hip_bfloat16* h1b = h1 + (size_t)z*NPTS*CWID;

  f32x4 acc[4][4] = {};

  for (int kt = 0; kt < 16; ++kt) {
    {
      const int k0_ = kt*EBK;
      // A: 1024 16B-units, 2 per thread
      #pragma unroll
      for (int qq = 0; qq < 2; ++qq) {
        const int cib = qq*512 + wid*64;     // wave-uniform dest base
        const int ci  = cib + lane;
        const int rw  = ci >> 3;
        const int oct = (ci & 7) ^ (rw & 7);
        async_copy16(h1b + (size_t)(m0 + rw)*CWID + k0_ + oct*8,
                     (__hip_bfloat16*)As + cib*8);
      }
      // B: 2048 16B-units, 4 per thread
      #pragma unroll
      for (int qq = 0; qq < 4; ++qq) {
        const int cib = qq*512 + wid*64;
        const int ci  = cib + lane;
        const int rw  = ci >> 3;
        const int oct = (ci & 7) ^ (rw & 7);
        async_copy16(w2t + (size_t)(n0 + rw)*CWID + k0_ + oct*8,
                     (__hip_bfloat16*)Bs + cib*8);
      }
    }
    __syncthreads();   // drains global_load_lds (vmcnt) + barrier: buffer ready
    #pragma unroll
    for (int ks = 0; ks < 2; ++ks) {
      const int ke = ks*32 + (lane >> 4)*8;
      const int ao = ke >> 3;
      bf16x8 a[4], bfr[4];
      #pragma unroll
      for (int f = 0; f < 4; ++f) {
        const int ar = wm*64 + f*16 + (lane & 15);
        const int br = wn*64 + f*16 + (lane & 15);
        a[f]   = *reinterpret_cast<const bf16x8*>((char*)As + (ar*8 + (ao ^ (ar & 7)))*16);
        bfr[f] = *reinterpret_cast<const bf16x8*>((char*)Bs + (br*8 + (ao ^ (br & 7)))*16);
      }
      #pragma unroll
      for (int fm = 0; fm < 4; ++fm)
        #pragma unroll
        for (int fn = 0; fn < 4; ++fn)
          acc[fm][fn] = __builtin_amdgcn_mfma_f32_16x16x32_bf16(a[fm], bfr[fn], acc[fm][fn], 0, 0, 0);
    }
    __syncthreads();   // all readers done before next STAGE overwrites
  }

  // epilogue: bias + relu + max over compacted rows (< nvb) -> atomicMax into c
  const int rbase = (lane >> 4)*4;
  #pragma unroll
  for (int fn = 0; fn < 4; ++fn) {
    const int gn = n0 + wn*64 + fn*16 + (lane & 15);
    const float bv = b2[gn];
    float mx = 0.f;
    #pragma unroll
    for (int fm = 0; fm < 4; ++fm) {
      const int gmb = m0 + wm*64 + fm*16 + rbase;
      #pragma unroll
      for (int r = 0; r < 4; ++r) {
        const float v = fmaxf(acc[fm][fn][r] + bv, 0.f);
        if (gmb + r < nvb) mx = fmaxf(mx, v);
      }
    }
    mx = fmaxf(mx, __shfl_xor(mx, 16));
    mx = fmaxf(mx, __shfl_xor(mx, 32));
    if ((lane >> 4) == 0)
      atomicMax((int*)(c + b*CWID + gn), __float_as_int(mx));  // values >= 0
  }
}

// ================= gamma/beta: stage A (split-K partials) =================
__global__ __launch_bounds__(256) void k_gbp(
    const float* __restrict__ c,
    const float* __restrict__ Wg0, const float* __restrict__ Wb0,
    const float* __restrict__ Wg1, const float* __restrict__ Wb1,
    const float* __restrict__ bnWg, const float* __restrict__ bnWb,
    float* __restrict__ gbp)
{
  __shared__ float cs[8][64];
  __shared__ float red[4][8][256];
  const int s  = blockIdx.y;
  const int kc = blockIdx.x;
  const int k0 = kc * 64;
  const int t  = threadIdx.x;

  const float* W;
  if      (s < 5)  W = Wg0 + (size_t)s*CWID*DWID;
  else if (s < 10) W = Wb0 + (size_t)(s-5)*CWID*DWID;
  else if (s < 15) W = Wg1 + (size_t)(s-10)*CWID*DWID;
  else if (s < 20) W = Wb1 + (size_t)(s-15)*CWID*DWID;
  else if (s == 20) W = bnWg;
  else              W = bnWb;

  {
    const int i0 = t*2;
    cs[i0 >> 6][i0 & 63]         = c[(i0 >> 6)*CWID + k0 + (i0 & 63)];
    cs[(i0+1) >> 6][(i0+1) & 63] = c[((i0+1) >> 6)*CWID + k0 + ((i0+1) & 63)];
  }
  __syncthreads();

  const int sub = t >> 6;
  const int c0  = (t & 63) * 4;
  f32x4 acc[8] = {};
  #pragma unroll
  for (int i = 0; i < 16; ++i) {
    const int kk = sub*16 + i;
    const f32x4 w = *reinterpret_cast<const f32x4*>(&W[(size_t)(k0 + kk)*DWID + c0]);
    #pragma unroll
    for (int b = 0; b < 8; ++b) acc[b] = acc[b] + w * cs[b][kk];
  }
  #pragma unroll
  for (int b = 0; b < 8; ++b)
    *reinterpret_cast<f32x4*>(&red[sub][b][c0]) = acc[b];
  __syncthreads();
  for (int b = 0; b < 8; ++b) {
    const float v = red[0][b][t] + red[1][b][t] + red[2][b][t] + red[3][b][t];
    gbp[(((size_t)s*16 + kc)*8 + b)*DWID + t] = v;
  }
}

// ================= gamma/beta: stage B (reduce + bias) =================
__global__ __launch_bounds__(256) void k_gbf(
    const float* __restrict__ gbp,
    const float* __restrict__ bg0, const float* __restrict__ bb0,
    const float* __restrict__ bg1, const float* __restrict__ bb1,
    const float* __restrict__ bnbg, const float* __restrict__ bnbb,
    float* __restrict__ gb)
{
  const int s = blockIdx.x;
  const int t = threadIdx.x;
  const float* bias;
  if      (s < 5)  bias = bg0 + s*DWID;
  else if (s < 10) bias = bb0 + (s-5)*DWID;
  else if (s < 15) bias = bg1 + (s-10)*DWID;
  else if (s < 20) bias = bb1 + (s-15)*DWID;
  else if (s == 20) bias = bnbg;
  else              bias = bnbb;
  const float bv = bias[t];
  for (int b = 0; b < 8; ++b) {
    float acc = bv;
    #pragma unroll
    for (int kc = 0; kc < 16; ++kc)
      acc += gbp[(((size_t)s*16 + kc)*8 + b)*DWID + t];
    gb[((size_t)s*8 + b)*DWID + t] = acc;
  }
}

// ======== fc_p (64 rows/block) + stat partials; net stored bf16 ========
__global__ __launch_bounds__(256) void k_fcp2(
    const float* __restrict__ qc, const float* __restrict__ inv_p99,
    const float* __restrict__ W, const float* __restrict__ bias,
    __hip_bfloat16* __restrict__ net, float* __restrict__ part)
{
  __shared__ float qs[192];
  const int blk = blockIdx.x;
  const int r0 = blk * 64;
  const int b = r0 >> 11;
  const int t = threadIdx.x;
  if (t < 192) qs[t] = qc[(size_t)r0*3 + t] * inv_p99[b];
  __syncthreads();
  const float w0 = W[t], w1 = W[DWID + t], w2 = W[2*DWID + t];
  const float bv = bias[t];
  float s = 0.f, q = 0.f;
  for (int m = 0; m < 64; ++m) {
    const float v = bv + qs[m*3]*w0 + qs[m*3+1]*w1 + qs[m*3+2]*w2;
    net[(size_t)(r0 + m)*DWID + t] = __float2bfloat16(v);
    s += v; q += v*v;
  }
  part[(size_t)t*NPBLK + blk] = s;
  part[(size_t)(256 + t)*NPBLK + blk] = q;
}

// ====== stats finalize (32 blocks x 8 cols; contiguous col-major reads) ======
__global__ __launch_bounds__(256) void k_statf(
    const float* __restrict__ part, float* __restrict__ stats)
{
  const int t = threadIdx.x;
  const int j = t >> 5;            // col within block (0..7)
  const int lane = t & 31;
  const int col = blockIdx.x * 8 + j;
  const float* ps = part + (size_t)col*NPBLK;
  const float* pq = part + (size_t)(256 + col)*NPBLK;
  f32x4 sv = {}, qv = {};
  #pragma unroll
  for (int i = 0; i < 2; ++i) {
    sv = sv + *reinterpret_cast<const f32x4*>(ps + i*128 + lane*4);
    qv = qv + *reinterpret_cast<const f32x4*>(pq + i*128 + lane*4);
  }
  float s = (sv[0]+sv[1]) + (sv[2]+sv[3]);
  float q = (qv[0]+qv[1]) + (qv[2]+qv[3]);
  #pragma unroll
  for (int o = 16; o > 0; o >>= 1) { s += __shfl_down(s, o); q += __shfl_down(q, o); }
  if (lane == 0) {
    const float mean = s * (1.f/16384.f);
    const float var  = q * (1.f/16384.f) - mean*mean;
    stats[col] = mean;
    stats[256 + col] = rsqrtf(var + 1e-5f);
  }
}

// ========== CBN + relu + MFMA matmul (+residual) + stat partials ==========
// X/out are bf16 (halved HBM traffic); all arithmetic stays f32.
__global__ __launch_bounds__(256) void k_cbnmm(
    const __hip_bfloat16* __restrict__ X, const float* __restrict__ stats,
    const float* __restrict__ gb, int gslot, int bslot,
    const __hip_bfloat16* __restrict__ wt,   // [256 n][256 k] bf16
    const float* __restrict__ bias,
    __hip_bfloat16* __restrict__ out, int addmode, float* __restrict__ part)
{
  __shared__ __align__(16) __hip_bfloat16 xs[64 * 256];  // swizzled [row][k], 32 KB
  __shared__ float sred[4][2][128];
  const int t = threadIdx.x;
  const int blk = blockIdx.x;
  const int r0 = blk * 64;
  const int bb = r0 >> 11;

  // ---- stage: CBN + relu + bf16, XOR-swizzled on 16B groups ----
  {
    const int cq = (t & 63) * 4;
    const f32x4 mn = *reinterpret_cast<const f32x4*>(&stats[cq]);
    const f32x4 rs = *reinterpret_cast<const f32x4*>(&stats[256 + cq]);
    const f32x4 g  = *reinterpret_cast<const f32x4*>(&gb[((size_t)gslot*8 + bb)*DWID + cq]);
    const f32x4 be = *reinterpret_cast<const f32x4*>(&gb[((size_t)bslot*8 + bb)*DWID + cq]);
    const int rbase = t >> 6;
    #pragma unroll
    for (int j = 0; j < 16; ++j) {
      const int r = rbase + j*4;
      const bf16x4 xv = *reinterpret_cast<const bf16x4*>(&X[(size_t)(r0 + r)*DWID + cq]);
      bf16x4 h;
      #pragma unroll
      for (int jj = 0; jj < 4; ++jj)
        h[jj] = (__bf16)fmaxf(0.f, ((float)xv[jj] - mn[jj])*rs[jj]*g[jj] + be[jj]);
      const int grp = (cq >> 3) ^ (r & 7);
      *reinterpret_cast<bf16x4*>((char*)xs + r*512 + grp*16 + (cq & 7)*2) = h;
    }
  }
  __syncthreads();

  const int lane = t & 63, wid = t >> 6;
  const int wm = wid >> 1, wn = wid & 1;
  f32x4 acc[2][8] = {};
  #pragma unroll
  for (int kstep = 0; kstep < 8; ++kstep) {
    const int ke = kstep*32 + (lane >> 4)*8;
    bf16x8 a[2], bfr[8];
    #pragma unroll
    for (int fm = 0; fm < 2; ++fm) {
      const int row = wm*32 + fm*16 + (lane & 15);
      a[fm] = *reinterpret_cast<const bf16x8*>(
          (char*)xs + row*512 + (((ke >> 3) ^ (row & 7))*16));
    }
    #pragma unroll
    for (int fn = 0; fn < 8; ++fn) {
      const int n = wn*128 + fn*16 + (lane & 15);
      bfr[fn] = *reinterpret_cast<const bf16x8*>(&wt[(size_t)n*DWID + ke]);
    }
    #pragma unroll
    for (int fm = 0; fm < 2; ++fm)
      #pragma unroll
      for (int fn = 0; fn < 8; ++fn)
        acc[fm][fn] = __builtin_amdgcn_mfma_f32_16x16x32_bf16(a[fm], bfr[fn], acc[fm][fn], 0, 0, 0);
  }

  // ---- epilogue: bias + residual + store (bf16) + per-block column sums ----
  const int rb = (lane >> 4) * 4;
  #pragma unroll
  for (int fn = 0; fn < 8; ++fn) {
    const int gn = wn*128 + fn*16 + (lane & 15);
    const float bv = bias[gn];
    float s = 0.f, q = 0.f;
    #pragma unroll
    for (int fm = 0; fm < 2; ++fm) {
      const size_t row0 = (size_t)r0 + wm*32 + fm*16 + rb;
      #pragma unroll
      for (int r = 0; r < 4; ++r) {
        float v = acc[fm][fn][r] + bv;
        if (addmode) v += (float)out[(row0 + r)*DWID + gn];
        out[(row0 + r)*DWID + gn] = __float2bfloat16(v);
        s += v; q += v*v;
      }
    }
    s += __shfl_xor(s, 16); s += __shfl_xor(s, 32);
    q += __shfl_xor(q, 16); q += __shfl_xor(q, 32);
    if ((lane >> 4) == 0) {
      sred[wid][0][fn*16 + (lane & 15)] = s;
      sred[wid][1][fn*16 + (lane & 15)] = q;
    }
  }
  __syncthreads();
  {
    const int col = t;           // 0..255
    const int wn2 = col >> 7, cl = col & 127;
    const float s = sred[wn2][0][cl] + sred[2 + wn2][0][cl];
    const float q = sred[wn2][1][cl] + sred[2 + wn2][1][cl];
    part[(size_t)col*NPBLK + blk] = s;
    part[(size_t)(256 + col)*NPBLK + blk] = q;
  }
}

// ================= final CBN + relu + fc_out (net is bf16) =================
__global__ __launch_bounds__(256) void k_final(
    const __hip_bfloat16* __restrict__ net, const float* __restrict__ stats,
    const float* __restrict__ gb, const float* __restrict__ fcW,
    const float* __restrict__ fcb, float* __restrict__ out)
{
  const int wid = threadIdx.x >> 6, lane = threadIdx.x & 63;
  const int m = blockIdx.x*4 + wid;
  const int b = m >> 11;
  const int f0 = lane*4;
  const bf16x4 xv = *reinterpret_cast<const bf16x4*>(&net[(size_t)m*DWID + f0]);
  const f32x4 mn = *reinterpret_cast<const f32x4*>(&stats[f0]);
  const f32x4 rs = *reinterpret_cast<const f32x4*>(&stats[256 + f0]);
  const f32x4 g  = *reinterpret_cast<const f32x4*>(&gb[(20*8 + (size_t)b)*DWID + f0]);
  const f32x4 be = *reinterpret_cast<const f32x4*>(&gb[(21*8 + (size_t)b)*DWID + f0]);
  const f32x4 w  = *reinterpret_cast<const f32x4*>(&fcW[f0]);
  float s = 0.f;
  #pragma unroll
  for (int j = 0; j < 4; ++j)
    s += fmaxf(0.f, ((float)xv[j] - mn[j])*rs[j]*g[j] + be[j]) * w[j];
  #pragma unroll
  for (int o = 32; o > 0; o >>= 1) s += __shfl_down(s, o);
  if (lane == 0) out[m] = s + fcb[0];
}

// ================= launch =================
extern "C" void kernel_launch(void* const* d_in, const int* in_sizes, int n_in,
                              void* d_out, int out_size, void* d_ws, size_t ws_size,
                              hipStream_t stream) {
  (void)in_sizes; (void)n_in; (void)out_size;
  if (ws_size < WS_NEEDED) return;

  const float* pts    = (const float*)d_in[0];
  const float* rgb    = (const float*)d_in[1];
  const float* qc     = (const float*)d_in[2];
  const float* enc_W1 = (const float*)d_in[3];
  const float* enc_b1 = (const float*)d_in[4];
  const float* enc_W2 = (const float*)d_in[5];
  const float* enc_b2 = (const float*)d_in[6];
  const float* fc_p_W = (const float*)d_in[7];
  const float* fc_p_b = (const float*)d_in[8];
  const float* Wg0 = (const float*)d_in[9];
  const float* bg0 = (const float*)d_in[10];
  const float* Wb0 = (const float*)d_in[11];
  const float* bb0 = (const float*)d_in[12];
  const float* W0  = (const float*)d_in[13];
  const float* b0  = (const float*)d_in[14];
  const float* Wg1 = (const float*)d_in[15];
  const float* bg1 = (const float*)d_in[16];
  const float* Wb1 = (const float*)d_in[17];
  const float* bb1 = (const float*)d_in[18];
  const float* W1  = (const float*)d_in[19];
  const float* b1  = (const float*)d_in[20];
  const float* bnWg = (const float*)d_in[21];
  const float* bnbg = (const float*)d_in[22];
  const float* bnWb = (const float*)d_in[23];
  const float* bnbb = (const float*)d_in[24];
  const float* fcoW = (const float*)d_in[25];
  const float* fcob = (const float*)d_in[26];
  float* out = (float*)d_out;

  char* ws = (char*)d_ws;
  float* inv_p99 = (float*)(ws + OFF_INV);
  float* c      = (float*)(ws + OFF_C);
  float* gbuf   = (float*)(ws + OFF_GB);
  float* stats  = (float*)(ws + OFF_STATS);
  __hip_bfloat16* w2t = (__hip_bfloat16*)(ws + OFF_W2T);
  __hip_bfloat16* wt  = (__hip_bfloat16*)(ws + OFF_WT);
  float* gbp  = (float*)(ws + OFF_GBP);
  float* part = (float*)(ws + OFF_PART);
  int*   idx  = (int*)(ws + OFF_IDX);
  int*   nvp  = (int*)(ws + OFF_NV);
  __hip_bfloat16* net = (__hip_bfloat16*)(ws + OFF_NET);
  __hip_bfloat16* dx  = (__hip_bfloat16*)(ws + OFF_DX);

  k_p99<<<NB, 1024, 0, stream>>>(pts, inv_p99, idx, nvp, c);
  k_prep<<<416, 256, 0, stream>>>(enc_W2, w2t, W0, W1, wt);

  if (ws_size >= WS_BIG) {
    // big path: full h1 at 64 MiB, single encoder launch over all 8 batches
    __hip_bfloat16* h1f = (__hip_bfloat16*)(ws + OFF_H1F);
    k_enc1<<<dim3(NPTS/E1R, NB), 256, 0, stream>>>(pts, rgb, inv_p99, idx, nvp,
                                                   enc_W1, enc_b1, h1f, 0);
    k_enc2<<<dim3(NPTS/EBM, CWID/EBN, NB), 512, 0, stream>>>(h1f, w2t, enc_b2,
                                                             nvp, c, 0);
  } else {
    // fallback: pair-looped encoder, h1 aliases net/dx
    __hip_bfloat16* h1 = (__hip_bfloat16*)(ws + OFF_H1);
    for (int bp = 0; bp < 4; ++bp) {
      k_enc1<<<dim3(NPTS/E1R, 2), 256, 0, stream>>>(pts, rgb, inv_p99, idx, nvp,
                                                    enc_W1, enc_b1, h1, bp*2);
      k_enc2<<<dim3(NPTS/EBM, CWID/EBN, 2), 512, 0, stream>>>(h1, w2t, enc_b2,
                                                              nvp, c, bp*2);
    }
  }

  k_gbp<<<dim3(16,22), 256, 0, stream>>>(c, Wg0, Wb0, Wg1, Wb1, bnWg, bnWb, gbp);
  k_gbf<<<22, 256, 0, stream>>>(gbp, bg0, bb0, bg1, bb1, bnbg, bnbb, gbuf);

  k_fcp2<<<NPBLK, 256, 0, stream>>>(qc, inv_p99, fc_p_W, fc_p_b, net, part);
  k_statf<<<32, 256, 0, stream>>>(part, stats);
  for (int i = 0; i < 5; ++i) {
    k_cbnmm<<<NPBLK, 256, 0, stream>>>(net, stats, gbuf, i, 5+i,
                                       wt + (size_t)i*DWID*DWID, b0 + i*DWID, dx, 0, part);
    k_statf<<<32, 256, 0, stream>>>(part, stats);
    k_cbnmm<<<NPBLK, 256, 0, stream>>>(dx, stats, gbuf, 10+i, 15+i,
                                       wt + (size_t)(5+i)*DWID*DWID, b1 + i*DWID, net, 1, part);
    k_statf<<<32, 256, 0, stream>>>(part, stats);
  }
  k_final<<<NB*NT/4, 256, 0, stream>>>(net, stats, gbuf, fcoW, fcob, out);
}